// Round 13
// baseline (133.073 us; speedup 1.0000x reference)
//
#include <hip/hip_runtime.h>
#include <hip/hip_bf16.h>

typedef unsigned short ushort_t;
typedef short short8 __attribute__((ext_vector_type(8)));
typedef float f32x4 __attribute__((ext_vector_type(4)));

#define B_  2
#define S_  4096
#define D_  512
#define H_  8
#define HD_ 64
#define DK_ 256
#define TOPK_ 256
#define KSLOTS_ 512   // 2*TOPK_ slots (union of both batches' top-k)

typedef __attribute__((address_space(1))) unsigned int g_u32;
typedef __attribute__((address_space(3))) unsigned int l_u32;

__device__ __forceinline__ float bf2f(ushort_t u) {
    unsigned int b = ((unsigned int)u) << 16;
    float f;
    __builtin_memcpy(&f, &b, 4);
    return f;
}
__device__ __forceinline__ ushort_t f2bf(float f) {
    unsigned int b;
    __builtin_memcpy(&b, &f, 4);
    b = (b + 0x7FFFu + ((b >> 16) & 1u)) >> 16;
    return (ushort_t)b;
}

// V column permutation: physical PV slot p <- stored K row s(p).
// Makes swapped-QK P register layout == MFMA A-fragment layout.
__device__ __forceinline__ int vperm(int p) {
    const int hi = p & ~63, p64 = p & 63;
    const int ks = p64 >> 5, a = (p64 >> 3) & 3, j = p64 & 7;
    return hi | ((2 * ks + (j >> 2)) * 16 + a * 4 + (j & 3));
}

// ---------------------------------------------------------------------------
// Fused prep: flat grid.
//  blocks [0, 2048):    x fp32 -> bf16 hi/lo pack (8 elem/thread)
//  blocks [2048, 3328): weight transposes fp32 -> bf16
//     z=0..3: Wq/Wk/Wv/Wo 512x512 -> W^T (z==0 pre-scaled by 0.125 = HD^-0.5)
//     z=4:    Ws1 512x256 -> Ws1^T hi/lo
// ---------------------------------------------------------------------------
__global__ __launch_bounds__(256) void prep_k(
    const float* __restrict__ x, ushort_t* __restrict__ xhi,
    ushort_t* __restrict__ xlo,
    const float* __restrict__ W0, const float* __restrict__ W1,
    const float* __restrict__ W2, const float* __restrict__ W3,
    const float* __restrict__ Ws1,
    ushort_t* __restrict__ O0, ushort_t* __restrict__ O1,
    ushort_t* __restrict__ O2, ushort_t* __restrict__ O3,
    ushort_t* __restrict__ s1hi, ushort_t* __restrict__ s1lo)
{
    if (blockIdx.x < 2048) {
        const long i = ((long)blockIdx.x * 256 + threadIdx.x) * 8;
        const float4 a = *(const float4*)(x + i);
        const float4 b = *(const float4*)(x + i + 4);
        float v[8] = {a.x, a.y, a.z, a.w, b.x, b.y, b.z, b.w};
        short8 oh, ol;
#pragma unroll
        for (int q = 0; q < 8; ++q) {
            const ushort_t h = f2bf(v[q]);
            oh[q] = (short)h;
            ol[q] = (short)f2bf(v[q] - bf2f(h));
        }
        *(short8*)(xhi + i) = oh;
        *(short8*)(xlo + i) = ol;
        return;
    }
    __shared__ float tile[32][33];
    const int idx = blockIdx.x - 2048;
    const int z = idx >> 8, rem = idx & 255;
    const int bx = rem & 15, by = rem >> 4;
    const int tx = threadIdx.x & 31, ty = threadIdx.x >> 5;  // 32 x 8
    const int c0 = bx * 32, r0 = by * 32;
    if (z == 4) {
        if (bx >= 8) return;  // Ws1 is 512x256
#pragma unroll
        for (int i = 0; i < 32; i += 8)
            tile[ty + i][tx] = Ws1[(long)(r0 + ty + i) * 256 + c0 + tx];
        __syncthreads();
#pragma unroll
        for (int i = 0; i < 32; i += 8) {
            const float v = tile[tx][ty + i];
            const ushort_t h = f2bf(v);
            const long o = (long)(c0 + ty + i) * 512 + r0 + tx;
            s1hi[o] = h;
            s1lo[o] = f2bf(v - bf2f(h));
        }
        return;
    }
    const float* in = (z == 0) ? W0 : (z == 1) ? W1 : (z == 2) ? W2 : W3;
    ushort_t*   out = (z == 0) ? O0 : (z == 1) ? O1 : (z == 2) ? O2 : O3;
    const float scale = (z == 0) ? 0.125f : 1.0f;  // fold HD^-0.5 into Wq (exact)
#pragma unroll
    for (int i = 0; i < 32; i += 8)
        tile[ty + i][tx] = in[(long)(r0 + ty + i) * 512 + c0 + tx];
    __syncthreads();
#pragma unroll
    for (int i = 0; i < 32; i += 8)
        out[(long)(c0 + ty + i) * 512 + r0 + tx] = f2bf(tile[tx][ty + i] * scale);
}

// ---------------------------------------------------------------------------
// imp via hi/lo bf16 MFMA (error ~1e-5 vs fp32, << top-k spacing):
// h = xhi@Whi + xhi@Wlo + xlo@Whi + bs1 (fp32 acc); imp = gelu(h) @ Ws2.
// v3: 512-thread blocks, 8 waves; wave = 16 tok x 64 j (2 waves/SIMD).
// ---------------------------------------------------------------------------
__global__ __launch_bounds__(512) void imp_mfma_k(
    const ushort_t* __restrict__ xhi, const ushort_t* __restrict__ xlo,
    const ushort_t* __restrict__ w1hi, const ushort_t* __restrict__ w1lo,
    const float* __restrict__ bs1, const float* __restrict__ Ws2,
    float* __restrict__ imp)
{
    __shared__ float red[8][16];
    const int tid = threadIdx.x, lane = tid & 63, w = tid >> 6;  // 8 waves
    const int l15 = lane & 15, l4 = lane >> 4;
    const int tok0 = blockIdx.x * 32 + (w >> 2) * 16;
    const int j0 = (w & 3) * 64;

    const ushort_t* a0h = xhi + (long)(tok0 + l15) * 512 + l4 * 8;
    const ushort_t* a0l = xlo + (long)(tok0 + l15) * 512 + l4 * 8;
    const ushort_t* bh0 = w1hi + (long)(j0 + l15) * 512 + l4 * 8;
    const ushort_t* bl0 = w1lo + (long)(j0 + l15) * 512 + l4 * 8;

    f32x4 acc[4];
#pragma unroll
    for (int c = 0; c < 4; ++c) {
        const float bv = bs1[j0 + c * 16 + l15];
#pragma unroll
        for (int r = 0; r < 4; ++r) acc[c][r] = bv;
    }

#pragma unroll 2
    for (int kk = 0; kk < 16; ++kk) {
        const int ko = kk * 32;
        const short8 A0 = *(const short8*)(a0h + ko);
        const short8 L0 = *(const short8*)(a0l + ko);
#pragma unroll
        for (int c = 0; c < 4; ++c) {
            const short8 Bh = *(const short8*)(bh0 + c * (16 * 512) + ko);
            const short8 Bl = *(const short8*)(bl0 + c * (16 * 512) + ko);
            acc[c] = __builtin_amdgcn_mfma_f32_16x16x32_bf16(A0, Bh, acc[c], 0, 0, 0);
            acc[c] = __builtin_amdgcn_mfma_f32_16x16x32_bf16(A0, Bl, acc[c], 0, 0, 0);
            acc[c] = __builtin_amdgcn_mfma_f32_16x16x32_bf16(L0, Bh, acc[c], 0, 0, 0);
        }
    }

    float ws2c[4];
#pragma unroll
    for (int c = 0; c < 4; ++c) ws2c[c] = Ws2[j0 + c * 16 + l15];
#pragma unroll
    for (int r = 0; r < 4; ++r) {
        float p = 0.0f;
#pragma unroll
        for (int c = 0; c < 4; ++c) {
            const float hv = acc[c][r];
            p = fmaf(0.5f * hv * (1.0f + erff(hv * 0.70710678118f)), ws2c[c], p);
        }
        p += __shfl_xor(p, 1); p += __shfl_xor(p, 2);
        p += __shfl_xor(p, 4); p += __shfl_xor(p, 8);
        if (l15 == 0) red[w][l4 * 4 + r] = p;
    }
    __syncthreads();
    if (tid < 32) {
        const int th = tid >> 4, row = tid & 15;
        imp[blockIdx.x * 32 + tid] =
            (red[th * 4 + 0][row] + red[th * 4 + 1][row]) +
            (red[th * 4 + 2][row] + red[th * 4 + 3][row]);
    }
}

// ---------------------------------------------------------------------------
// Per-batch exact top-k via radix-select, then index-ordered tie resolution
// (matches jax.lax.top_k selected SET). One block (1024 thr) per batch.
// ---------------------------------------------------------------------------
__global__ __launch_bounds__(1024) void topk_select_k(
    const float* __restrict__ imp, unsigned char* __restrict__ sel)
{
    __shared__ unsigned int keys[4096];
    __shared__ unsigned int hist[256];
    __shared__ int chunkscan[64];
    __shared__ unsigned int sh_prefix;
    __shared__ int sh_rem;
    const int b = blockIdx.x, tid = threadIdx.x;
    const int lane = tid & 63, w = tid >> 6;
    for (int i = tid; i < 4096; i += 1024) {
        const unsigned int u = __float_as_uint(imp[b * 4096 + i]);
        keys[i] = (u & 0x80000000u) ? ~u : (u | 0x80000000u);  // order-preserving
    }
    if (tid == 0) { sh_prefix = 0u; sh_rem = TOPK_; }
    __syncthreads();
    unsigned int pmask = 0;
    for (int level = 3; level >= 0; --level) {
        const int shb = level * 8;
        const unsigned int prefix = sh_prefix;
        const int remaining = sh_rem;
        if (tid < 256) hist[tid] = 0;
        __syncthreads();
        for (int i = tid; i < 4096; i += 1024) {
            const unsigned int u = keys[i];
            if ((u & pmask) == prefix) atomicAdd(&hist[(u >> shb) & 255u], 1u);
        }
        __syncthreads();
        if (tid < 64) {
            unsigned int v[4];
            int tot = 0;
#pragma unroll
            for (int q = 0; q < 4; ++q) { v[q] = hist[255 - (tid * 4 + q)]; tot += (int)v[q]; }
            int pre = tot;
            for (int off = 1; off < 64; off <<= 1) {
                const int t = __shfl_up(pre, off);
                if (tid >= off) pre += t;
            }
            const unsigned long long bal = __ballot(pre >= remaining);
            const int L = __ffsll((unsigned long long)bal) - 1;
            if (tid == L) {
                int c = pre - tot;
#pragma unroll
                for (int q = 0; q < 4; ++q) {
                    c += (int)v[q];
                    if (c >= remaining) {
                        sh_rem = remaining - (c - (int)v[q]);
                        sh_prefix = prefix | ((unsigned int)(255 - (tid * 4 + q)) << shb);
                        break;
                    }
                }
            }
        }
        __syncthreads();
        pmask |= (255u << shb);
    }
    const unsigned int T = sh_prefix;
    const int need = sh_rem;  // how many == T elements to take (index asc)
#pragma unroll
    for (int q = 0; q < 4; ++q) {
        const int chunk = w * 4 + q;
        const unsigned long long bal = __ballot(keys[chunk * 64 + lane] == T);
        if (lane == 0) chunkscan[chunk] = __popcll(bal);
    }
    __syncthreads();
    if (tid < 64) {
        const int v = chunkscan[tid];
        int pre = v;
        for (int off = 1; off < 64; off <<= 1) {
            const int t = __shfl_up(pre, off);
            if (tid >= off) pre += t;
        }
        chunkscan[tid] = pre - v;  // exclusive prefix
    }
    __syncthreads();
#pragma unroll
    for (int q = 0; q < 4; ++q) {
        const int chunk = w * 4 + q;
        const int i = chunk * 64 + lane;
        const unsigned int u = keys[i];
        const bool eq = (u == T);
        const unsigned long long bal = __ballot(eq);
        const int rank = chunkscan[chunk] + __popcll(bal & ((1ull << lane) - 1ull));
        sel[b * 4096 + i] = (u > T || (eq && rank < need)) ? 1 : 0;
    }
}

// ---------------------------------------------------------------------------
// Union of selections -> compacted ascending column list + gather rowmap.
// Lane-parallel: lane i owns tokens i*64..i*64+63 (bitmask + shfl scan).
// ---------------------------------------------------------------------------
__global__ void compact_k(const unsigned char* __restrict__ sel,
                          int* __restrict__ rowmap, int* __restrict__ keffp)
{
    const int lane = threadIdx.x;  // 64 threads = 1 wave
    const unsigned long long* p0 = (const unsigned long long*)(sel);
    const unsigned long long* p1 = (const unsigned long long*)(sel + 4096);
    unsigned long long bits = 0;
#pragma unroll
    for (int q = 0; q < 8; ++q) {
        const unsigned long long u = p0[lane * 8 + q] | p1[lane * 8 + q];
        unsigned long long b8 = 0;
#pragma unroll
        for (int j = 0; j < 8; ++j) b8 |= ((u >> (8 * j)) & 1ull) << j;
        bits |= b8 << (8 * q);
    }
    const int cnt = __popcll(bits);
    int pre = cnt;
    for (int off = 1; off < 64; off <<= 1) {
        const int t = __shfl_up(pre, off);
        if (lane >= off) pre += t;
    }
    const int total = __shfl(pre, 63);
    int ofs = pre - cnt;  // exclusive prefix
    unsigned long long m = bits;
    while (m) {
        const int j = __ffsll(m) - 1;
        const int pos = lane * 64 + j;
        rowmap[ofs] = pos;                  // batch 0 token row
        rowmap[KSLOTS_ + ofs] = 4096 + pos; // batch 1 token row
        ++ofs;
        m &= m - 1;
    }
    for (int s = total + lane; s < KSLOTS_; s += 64) {
        rowmap[s] = 0; rowmap[KSLOTS_ + s] = 4096;  // pad -> token 0 (masked)
    }
    if (lane == 0) keffp[0] = total;
}

// ---------------------------------------------------------------------------
// Merged K-proj + V^T-proj (one launch, flat grid of 128 blocks).
//  id < 64:  k_sel[s][512] = xb[rowmap[s]] @ Wk + bk     (M=1024, tiles 8x8)
//  id >= 64: vT[d][col]   = Wv^T[d] . xb[rowmap[vperm(col)]] + bv[d]
// ---------------------------------------------------------------------------
__global__ __launch_bounds__(256) void gemm_kv_k(
    const ushort_t* __restrict__ xb,
    const ushort_t* __restrict__ WkT, const float* __restrict__ bk,
    ushort_t* __restrict__ k_sel,
    const ushort_t* __restrict__ WvT, const float* __restrict__ bv,
    ushort_t* __restrict__ vT, const int* __restrict__ rowmap)
{
    const int K = 512;
    const int tid = threadIdx.x, lane = tid & 63, w = tid >> 6;
    const int l15 = lane & 15, l4 = lane >> 4;
    const int id = blockIdx.x;

    if (id < 64) {
        const int m_base = (id & 7) * 128 + w * 32;
        const int n_base = (id >> 3) * 64;
        const long ar0 = (long)rowmap[m_base + l15];
        const long ar1 = (long)rowmap[m_base + 16 + l15];
        const ushort_t* a0p = xb + ar0 * K + l4 * 8;
        const ushort_t* a1p = xb + ar1 * K + l4 * 8;
        const ushort_t* bp0 = WkT + (long)(n_base +  0 + l15) * K + l4 * 8;
        const ushort_t* bp1 = WkT + (long)(n_base + 16 + l15) * K + l4 * 8;
        const ushort_t* bp2 = WkT + (long)(n_base + 32 + l15) * K + l4 * 8;
        const ushort_t* bp3 = WkT + (long)(n_base + 48 + l15) * K + l4 * 8;
        f32x4 acc[2][4] = {};
#pragma unroll 4
        for (int kk = 0; kk < 16; ++kk) {
            const int ko = kk * 32;
            const short8 a0 = *(const short8*)(a0p + ko);
            const short8 a1 = *(const short8*)(a1p + ko);
            const short8 b0 = *(const short8*)(bp0 + ko);
            const short8 b1 = *(const short8*)(bp1 + ko);
            const short8 b2 = *(const short8*)(bp2 + ko);
            const short8 b3 = *(const short8*)(bp3 + ko);
            acc[0][0] = __builtin_amdgcn_mfma_f32_16x16x32_bf16(a0, b0, acc[0][0], 0, 0, 0);
            acc[1][0] = __builtin_amdgcn_mfma_f32_16x16x32_bf16(a1, b0, acc[1][0], 0, 0, 0);
            acc[0][1] = __builtin_amdgcn_mfma_f32_16x16x32_bf16(a0, b1, acc[0][1], 0, 0, 0);
            acc[1][1] = __builtin_amdgcn_mfma_f32_16x16x32_bf16(a1, b1, acc[1][1], 0, 0, 0);
            acc[0][2] = __builtin_amdgcn_mfma_f32_16x16x32_bf16(a0, b2, acc[0][2], 0, 0, 0);
            acc[1][2] = __builtin_amdgcn_mfma_f32_16x16x32_bf16(a1, b2, acc[1][2], 0, 0, 0);
            acc[0][3] = __builtin_amdgcn_mfma_f32_16x16x32_bf16(a0, b3, acc[0][3], 0, 0, 0);
            acc[1][3] = __builtin_amdgcn_mfma_f32_16x16x32_bf16(a1, b3, acc[1][3], 0, 0, 0);
        }
#pragma unroll
        for (int g = 0; g < 2; ++g)
#pragma unroll
            for (int c = 0; c < 4; ++c) {
                const int col = n_base + c * 16 + l15;
                const float bvv = bk[col];
#pragma unroll
                for (int r = 0; r < 4; ++r) {
                    const int row = m_base + g * 16 + l4 * 4 + r;
                    k_sel[(long)row * 512 + col] = f2bf(acc[g][c][r] + bvv);
                }
            }
    } else {
        const int vid = id - 64;
        const int m_base = (vid & 3) * 128 + w * 32;   // d
        const int n_base = (vid >> 2) * 64;            // b*512+slot (physical)
        const ushort_t* a0p = WvT + (long)(m_base + l15) * K + l4 * 8;
        const ushort_t* a1p = WvT + (long)(m_base + 16 + l15) * K + l4 * 8;
        const long c0 = rowmap[vperm(n_base +  0 + l15)];
        const long c1 = rowmap[vperm(n_base + 16 + l15)];
        const long c2 = rowmap[vperm(n_base + 32 + l15)];
        const long c3 = rowmap[vperm(n_base + 48 + l15)];
        const ushort_t* bp0 = xb + c0 * K + l4 * 8;
        const ushort_t* bp1 = xb + c1 * K + l4 * 8;
        const ushort_t* bp2 = xb + c2 * K + l4 * 8;
        const ushort_t* bp3 = xb + c3 * K + l4 * 8;
        f32x4 acc[2][4] = {};
#pragma unroll 4
        for (int kk = 0; kk < 16; ++kk) {
            const int ko = kk * 32;
            const short8 a0 = *(const short8*)(a0p + ko);
            const short8 a1 = *(const short8*)(a1p + ko);
            const short8 b0 = *(const short8*)(bp0 + ko);
            const short8 b1 = *(const short8*)(bp1 + ko);
            const short8 b2 = *(const short8*)(bp2 + ko);
            const short8 b3 = *(const short8*)(bp3 + ko);
            acc[0][0] = __builtin_amdgcn_mfma_f32_16x16x32_bf16(a0, b0, acc[0][0], 0, 0, 0);
            acc[1][0] = __builtin_amdgcn_mfma_f32_16x16x32_bf16(a1, b0, acc[1][0], 0, 0, 0);
            acc[0][1] = __builtin_amdgcn_mfma_f32_16x16x32_bf16(a0, b1, acc[0][1], 0, 0, 0);
            acc[1][1] = __builtin_amdgcn_mfma_f32_16x16x32_bf16(a1, b1, acc[1][1], 0, 0, 0);
            acc[0][2] = __builtin_amdgcn_mfma_f32_16x16x32_bf16(a0, b2, acc[0][2], 0, 0, 0);
            acc[1][2] = __builtin_amdgcn_mfma_f32_16x16x32_bf16(a1, b2, acc[1][2], 0, 0, 0);
            acc[0][3] = __builtin_amdgcn_mfma_f32_16x16x32_bf16(a0, b3, acc[0][3], 0, 0, 0);
            acc[1][3] = __builtin_amdgcn_mfma_f32_16x16x32_bf16(a1, b3, acc[1][3], 0, 0, 0);
        }
#pragma unroll
        for (int g = 0; g < 2; ++g)
#pragma unroll
            for (int r = 0; r < 4; ++r) {
                const int row = m_base + g * 16 + l4 * 4 + r;  // d
                const float bvv = bv[row];
#pragma unroll
                for (int c = 0; c < 4; ++c) {
                    const int col = n_base + c * 16 + l15;
                    vT[(long)row * 1024 + col] = f2bf(acc[g][c][r] + bvv);
                }
            }
    }
}

// ---------------------------------------------------------------------------
// LDS-staged GEMM (verified r8/r9 single-buffer): C = A @ W + bias*bscale.
// Tile 128x64, BK=64. global_load_lds width=16 with T2 XOR swizzle
// (pre-swizzled global source + swizzled ds_read — both-sides rule #21).
// ---------------------------------------------------------------------------
__global__ __launch_bounds__(256) void gemm128_k(
    const ushort_t* __restrict__ A, const ushort_t* __restrict__ WT,
    const float* __restrict__ bias, float bscale,
    ushort_t* __restrict__ Cb, float* __restrict__ Cf)
{
    __shared__ __align__(16) ushort_t Al[128 * 64];
    __shared__ __align__(16) ushort_t Bl[64 * 64];
    const int tid = threadIdx.x, lane = tid & 63, w = tid >> 6;
    const int l15 = lane & 15, l4 = lane >> 4;
    const int m0 = blockIdx.x * 128, n0 = blockIdx.y * 64;
    const int row_off = lane >> 3, kq = lane & 7;      // staging lane roles
    const int src_k8 = (kq ^ row_off) * 8;             // inverse-swizzled source

    f32x4 acc[2][4] = {};
#pragma unroll 1
    for (int kt = 0; kt < 8; ++kt) {
        __syncthreads();  // all waves done reading previous tile
#pragma unroll
        for (int i = 0; i < 4; ++i) {
            const int ia = w * 4 + i;
            const long ga = (long)(m0 + ia * 8 + row_off) * 512 + kt * 64 + src_k8;
            __builtin_amdgcn_global_load_lds((const g_u32*)(A + ga),
                                             (l_u32*)(Al + ia * 512), 16, 0, 0);
        }
#pragma unroll
        for (int i = 0; i < 2; ++i) {
            const int ib = w * 2 + i;
            const long gb = (long)(n0 + ib * 8 + row_off) * 512 + kt * 64 + src_k8;
            __builtin_amdgcn_global_load_lds((const g_u32*)(WT + gb),
                                             (l_u32*)(Bl + ib * 512), 16, 0, 0);
        }
        __syncthreads();  // tile ready (compiler drains vmcnt before barrier)
#pragma unroll
        for (int kh = 0; kh < 2; ++kh) {
            short8 af[2], bfr[4];
#pragma unroll
            for (int t = 0; t < 2; ++t) {
                const int row = w * 32 + t * 16 + l15;
                const int c8 = (kh * 4 + l4) ^ (row & 7);
                af[t] = *(const short8*)(Al + row * 64 + c8 * 8);
            }
#pragma unroll
            for (int u = 0; u < 4; ++u) {
                const int col = u * 16 + l15;
                const int c8 = (kh * 4 + l4) ^ (col & 7);
                bfr[u] = *(const short8*)(Bl + col * 64 + c8 * 8);
            }
#pragma unroll
            for (int t = 0; t < 2; ++t)
#pragma unroll
                for (int u = 0; u < 4; ++u)
                    acc[t][u] = __builtin_amdgcn_mfma_f32_16x16x32_bf16(
                        af[t], bfr[u], acc[t][u], 0, 0, 0);
        }
    }
#pragma unroll
    for (int t = 0; t < 2; ++t)
#pragma unroll
        for (int u = 0; u < 4; ++u) {
            const int col = n0 + u * 16 + l15;
            const float bv = bias[col] * bscale;
#pragma unroll
            for (int r = 0; r < 4; ++r) {
                const int row = m0 + w * 32 + t * 16 + l4 * 4 + r;
                const float val = acc[t][u][r] + bv;
                if (Cf) Cf[(long)row * 512 + col] = val;
                else    Cb[(long)row * 512 + col] = f2bf(val);
            }
        }
}

// ---------------------------------------------------------------------------
// Flash attention v5h: r9-verified v5 math (__expf domain, 0.125 scale) with
// K/V fragment loads hoisted to tile top (value-identical scheduling).
// Swapped QK^T (q lane-local) + pre-permuted V => P register-resident.
// Grid = B*H*(S/128) = 512 blocks; 4 waves x 32 q-rows.
// ---------------------------------------------------------------------------
__global__ __launch_bounds__(256) void attn_k(
    const ushort_t* __restrict__ q_all, const ushort_t* __restrict__ k_sel,
    const ushort_t* __restrict__ vT, const int* __restrict__ keff_p,
    ushort_t* __restrict__ att)
{
    const int tid = threadIdx.x;
    const int lane = tid & 63, w = tid >> 6;
    const int l15 = lane & 15, l4 = lane >> 4;
    const int bidx = blockIdx.x;
    const int qt = bidx & 31, h = (bidx >> 5) & 7, b = bidx >> 8;
    const int q0 = qt * 128;
    const int keff = keff_p[0];
    const int nfull = keff >> 6;
    const int ntiles = (keff + 63) >> 6;

    // Q fragments (B operand; input col = q = l15)
    short8 qf[2][2];
#pragma unroll
    for (int g = 0; g < 2; ++g) {
        const ushort_t* qrow =
            q_all + (long)(b * 4096 + q0 + w * 32 + g * 16 + l15) * 512 + h * 64;
#pragma unroll
        for (int ks = 0; ks < 2; ++ks)
            qf[g][ks] = *(const short8*)(qrow + ks * 32 + l4 * 8);
    }

    f32x4 acc[2][4] = {};
    float mrun[2] = {-3.0e38f, -3.0e38f};
    float lrun[2] = {0.0f, 0.0f};

#pragma unroll 1
    for (int t = 0; t < ntiles; ++t) {
        // ---- issue ALL K and V fragment loads up front (T14 in-tile) ----
        short8 kf[4][2], vf[4][2];
#pragma unroll
        for (int c = 0; c < 4; ++c) {
            const ushort_t* krow =
                k_sel + (long)(b * KSLOTS_ + t * 64 + c * 16 + l15) * 512 + h * 64;
            kf[c][0] = *(const short8*)(krow + l4 * 8);
            kf[c][1] = *(const short8*)(krow + 32 + l4 * 8);
        }
#pragma unroll
        for (int cd = 0; cd < 4; ++cd) {
            const ushort_t* vrow =
                vT + (long)(h * 64 + cd * 16 + l15) * 1024 + b * 512 + t * 64;
            vf[cd][0] = *(const short8*)(vrow + l4 * 8);
            vf[cd][1] = *(const short8*)(vrow + 32 + l4 * 8);
        }
        // ---- swapped scores: D[key][q], q = l15, key = c*16 + l4*4 + r ----
        f32x4 s[2][4] = {};
#pragma unroll
        for (int c = 0; c < 4; ++c)
#pragma unroll
            for (int ks = 0; ks < 2; ++ks) {
                s[0][c] = __builtin_amdgcn_mfma_f32_16x16x32_bf16(kf[c][ks], qf[0][ks], s[0][c], 0, 0, 0);
                s[1][c] = __builtin_amdgcn_mfma_f32_16x16x32_bf16(kf[c][ks], qf[1][ks], s[1][c], 0, 0, 0);
            }
        // ---- pad mask (stored-row coords), partial tile only ----
        if (t >= nfull) {
            const int rbase = t * 64 + l4 * 4;
#pragma unroll
            for (int c = 0; c < 4; ++c)
#pragma unroll
                for (int r = 0; r < 4; ++r) {
                    const bool valid = (rbase + c * 16 + r) < keff;
                    s[0][c][r] = valid ? s[0][c][r] : -1.0e30f;
                    s[1][c][r] = valid ? s[1][c][r] : -1.0e30f;
                }
        }
        // ---- per-thread row stats (all 16 values share q = l15) ----
        float mn[2];
        bool chg = false;
#pragma unroll
        for (int g = 0; g < 2; ++g) {
            float rm = -3.0e38f;
#pragma unroll
            for (int c = 0; c < 4; ++c)
                rm = fmaxf(rm, fmaxf(fmaxf(s[g][c][0], s[g][c][1]),
                                     fmaxf(s[g][c][2], s[g][c][3])));
            rm = fmaxf(rm, __shfl_xor(rm, 16));
            rm = fmaxf(rm, __shfl_xor(rm, 32));
            mn[g] = (rm > mrun[g] + 8.0f) ? rm : mrun[g];  // defer-max THR=8
            chg |= (mn[g] != mrun[g]);
        }
        if (__any(chg)) {
#pragma unroll
            for (int g = 0; g < 2; ++g) {
                const float sc = __expf(mrun[g] - mn[g]);
                lrun[g] *= sc;
#pragma unroll
                for (int r = 0; r < 4; ++r) {
                    const float scr = __shfl(sc, l4 * 4 + r);  // q of acc row r
#pragma unroll
                    for (int cd = 0; cd < 4; ++cd) acc[g][cd][r] *= scr;
                }
            }
        }
        mrun[0] = mn[0]; mrun[1] = mn[1];
#pragma unroll
        for (int g = 0; g < 2; ++g) {
            float rs = 0.0f;
#pragma unroll
            for (int c = 0; c < 4; ++c)
#pragma unroll
                for (int r = 0; r < 4; ++r) {
                    const float e = __expf(s[g][c][r] - mrun[g]);
                    s[g][c][r] = e;
                    rs += e;
                }
            rs += __shfl_xor(rs, 16);
            rs += __shfl_xor(rs, 32);
            lrun[g] += rs;
        }
        // ---- pack P into bf16 A-fragments (register-only; V pre-permuted) ----
        short8 pf[2][2];
#pragma unroll
        for (int g = 0; g < 2; ++g)
#pragma unroll
            for (int ks = 0; ks < 2; ++ks) {
                union { unsigned int u[4]; short8 v; } uu;
                asm("v_cvt_pk_bf16_f32 %0, %1, %2"
                    : "=v"(uu.u[0]) : "v"(s[g][2 * ks][0]), "v"(s[g][2 * ks][1]));
                asm("v_cvt_pk_bf16_f32 %0, %1, %2"
                    : "=v"(uu.u[1]) : "v"(s[g][2 * ks][2]), "v"(s[g][2 * ks][3]));
                asm("v_cvt_pk_bf16_f32 %0, %1, %2"
                    : "=v"(uu.u[2]) : "v"(s[g][2 * ks + 1][0]), "v"(s[g][2 * ks + 1][1]));
                asm("v_cvt_pk_bf16_f32 %0, %1, %2"
                    : "=v"(uu.u[3]) : "v"(s[g][2 * ks + 1][2]), "v"(s[g][2 * ks + 1][3]));
                pf[g][ks] = uu.v;
            }
        // ---- PV: O += P @ V ----
#pragma unroll
        for (int cd = 0; cd < 4; ++cd)
#pragma unroll
            for (int ks = 0; ks < 2; ++ks) {
                acc[0][cd] = __builtin_amdgcn_mfma_f32_16x16x32_bf16(pf[0][ks], vf[cd][ks], acc[0][cd], 0, 0, 0);
                acc[1][cd] = __builtin_amdgcn_mfma_f32_16x16x32_bf16(pf[1][ks], vf[cd][ks], acc[1][cd], 0, 0, 0);
            }
    }
    // ---- normalize + store: acc row r has q = l4*4 + r ----
#pragma unroll
    for (int g = 0; g < 2; ++g)
#pragma unroll
        for (int r = 0; r < 4; ++r) {
            const float lr = __shfl(lrun[g], l4 * 4 + r);
            const float inv = 1.0f / lr;
            const int row = q0 + w * 32 + g * 16 + l4 * 4 + r;
#pragma unroll
            for (int cd = 0; cd < 4; ++cd)
                att[(long)(b * 4096 + row) * 512 + h * 64 + cd * 16 + l15] =
                    f2bf(acc[g][cd][r] * inv);
        }
}

// ---------------------------------------------------------------------------
extern "C" void kernel_launch(void* const* d_in, const int* in_sizes, int n_in,
                              void* d_out, int out_size, void* d_ws, size_t ws_size,
                              hipStream_t stream)
{
    const float* x   = (const float*)d_in[0];
    const float* Wq  = (const float*)d_in[1];
    const float* bq  = (const float*)d_in[2];
    const float* Wk  = (const float*)d_in[3];
    const float* bk  = (const float*)d_in[4];
    const float* Wv  = (const float*)d_in[5];
    const float* bv  = (const float*)d_in[6];
    const float* Wo  = (const float*)d_in[7];
    const float* bo  = (const float*)d_in[8];
    const float* Ws1 = (const float*)d_in[9];
    const float* bs1 = (const float*)d_in[10];
    const float* Ws2 = (const float*)d_in[11];
    // d_in[12] = bs2 (selection-invariant, unused), d_in[13] = top_k (=256)

    char* ws = (char*)d_ws;
    float*          imp    = (float*)(ws + 0);              // 32 KB
    unsigned char*  sel    = (unsigned char*)(ws + 0x8000); // 8 KB
    int*            keffp  = (int*)(ws + 0xA800);
    int*            rowmap = (int*)(ws + 0xB000);           // 4 KB
    ushort_t*  WqT    = (ushort_t*)(ws + 0x40000);          // 4 x 512 KB
    ushort_t*  WkT    = WqT + 512 * 512;
    ushort_t*  WvT    = WkT + 512 * 512;
    ushort_t*  WoT    = WvT + 512 * 512;
    ushort_t*  k_sel  = (ushort_t*)(ws + 0x240000);         // 1 MB
    ushort_t*  vT     = (ushort_t*)(ws + 0x340000);         // 1 MB
    ushort_t*  w1hi   = (ushort_t*)(ws + 0x440000);         // 256 KB
    ushort_t*  w1lo   = (ushort_t*)(ws + 0x480000);         // 256 KB
    ushort_t*  xb     = (ushort_t*)(ws + 0x600000);         // 8 MB (= x_hi; reused as att)
    ushort_t*  att    = xb;                                 // dead after projections
    ushort_t*  xlo    = (ushort_t*)(ws + 0xE00000);         // 8 MB (reused as q_all)
    ushort_t*  q_all  = xlo;                                // xlo dead after imp_mfma

    const dim3 tblk(256);
    // 1. fused prep: x hi/lo pack + all weight transposes (Wq scaled 0.125)
    prep_k<<<3328, tblk, 0, stream>>>(x, xb, xlo, Wq, Wk, Wv, Wo, Ws1,
                                      WqT, WkT, WvT, WoT, w1hi, w1lo);
    // 2. importance via hi/lo MFMA (selection-exact vs fp32), 8-wave blocks
    imp_mfma_k<<<256, dim3(512), 0, stream>>>(xb, xlo, w1hi, w1lo, bs1, Ws2, imp);
    // 3. per-batch top-k via radix select
    topk_select_k<<<2, 1024, 0, stream>>>(imp, sel);
    // 4. union mask -> compacted column list + gather map (lane-parallel)
    compact_k<<<1, 64, 0, stream>>>(sel, rowmap, keffp);
    // 5. projections: LDS-staged dense Q (0.125-scaled; overwrites xlo — dead),
    //    merged gathered K + permuted V^T
    gemm128_k<<<dim3(64, 8), tblk, 0, stream>>>(xb, WqT, bq, 0.125f, q_all, nullptr);
    gemm_kv_k<<<128, tblk, 0, stream>>>(xb, WkT, bk, k_sel, WvT, bv, vT, rowmap);
    // 6. sparse flash attention v5h (att overwrites xb region — xb is dead now)
    attn_k<<<512, tblk, 0, stream>>>(q_all, k_sel, vT, keffp, att);
    // 7. output projection (LDS-staged) -> d_out (fp32)
    gemm128_k<<<dim3(64, 8), tblk, 0, stream>>>(att, WoT, bo, 1.0f, nullptr, (float*)d_out);
}

// Round 14
// 124.652 us; speedup vs baseline: 1.0676x; 1.0676x over previous
//
#include <hip/hip_runtime.h>
#include <hip/hip_bf16.h>

typedef unsigned short ushort_t;
typedef short short8 __attribute__((ext_vector_type(8)));
typedef float f32x4 __attribute__((ext_vector_type(4)));

#define B_  2
#define S_  4096
#define D_  512
#define H_  8
#define HD_ 64
#define DK_ 256
#define TOPK_ 256
#define KSLOTS_ 512   // 2*TOPK_ slots (union of both batches' top-k)

typedef __attribute__((address_space(1))) unsigned int g_u32;
typedef __attribute__((address_space(3))) unsigned int l_u32;

__device__ __forceinline__ float bf2f(ushort_t u) {
    unsigned int b = ((unsigned int)u) << 16;
    float f;
    __builtin_memcpy(&f, &b, 4);
    return f;
}
__device__ __forceinline__ ushort_t f2bf(float f) {
    unsigned int b;
    __builtin_memcpy(&b, &f, 4);
    b = (b + 0x7FFFu + ((b >> 16) & 1u)) >> 16;
    return (ushort_t)b;
}

// V column permutation: physical PV slot p <- stored K row s(p).
// Makes swapped-QK P register layout == MFMA A-fragment layout.
__device__ __forceinline__ int vperm(int p) {
    const int hi = p & ~63, p64 = p & 63;
    const int ks = p64 >> 5, a = (p64 >> 3) & 3, j = p64 & 7;
    return hi | ((2 * ks + (j >> 2)) * 16 + a * 4 + (j & 3));
}

// ---------------------------------------------------------------------------
// Fused prep: flat grid.
//  blocks [0, 2048):    x fp32 -> bf16 hi/lo pack (8 elem/thread)
//  blocks [2048, 3328): weight transposes fp32 -> bf16
//     z=0..3: Wq/Wk/Wv/Wo 512x512 -> W^T (z==0 pre-scaled by 0.125)
//     z=4:    Ws1 512x256 -> Ws1^T hi/lo
// ---------------------------------------------------------------------------
__global__ __launch_bounds__(256) void prep_k(
    const float* __restrict__ x, ushort_t* __restrict__ xhi,
    ushort_t* __restrict__ xlo,
    const float* __restrict__ W0, const float* __restrict__ W1,
    const float* __restrict__ W2, const float* __restrict__ W3,
    const float* __restrict__ Ws1,
    ushort_t* __restrict__ O0, ushort_t* __restrict__ O1,
    ushort_t* __restrict__ O2, ushort_t* __restrict__ O3,
    ushort_t* __restrict__ s1hi, ushort_t* __restrict__ s1lo)
{
    if (blockIdx.x < 2048) {
        const long i = ((long)blockIdx.x * 256 + threadIdx.x) * 8;
        const float4 a = *(const float4*)(x + i);
        const float4 b = *(const float4*)(x + i + 4);
        float v[8] = {a.x, a.y, a.z, a.w, b.x, b.y, b.z, b.w};
        short8 oh, ol;
#pragma unroll
        for (int q = 0; q < 8; ++q) {
            const ushort_t h = f2bf(v[q]);
            oh[q] = (short)h;
            ol[q] = (short)f2bf(v[q] - bf2f(h));
        }
        *(short8*)(xhi + i) = oh;
        *(short8*)(xlo + i) = ol;
        return;
    }
    __shared__ float tile[32][33];
    const int idx = blockIdx.x - 2048;
    const int z = idx >> 8, rem = idx & 255;
    const int bx = rem & 15, by = rem >> 4;
    const int tx = threadIdx.x & 31, ty = threadIdx.x >> 5;  // 32 x 8
    const int c0 = bx * 32, r0 = by * 32;
    if (z == 4) {
        if (bx >= 8) return;  // Ws1 is 512x256
#pragma unroll
        for (int i = 0; i < 32; i += 8)
            tile[ty + i][tx] = Ws1[(long)(r0 + ty + i) * 256 + c0 + tx];
        __syncthreads();
#pragma unroll
        for (int i = 0; i < 32; i += 8) {
            const float v = tile[tx][ty + i];
            const ushort_t h = f2bf(v);
            const long o = (long)(c0 + ty + i) * 512 + r0 + tx;
            s1hi[o] = h;
            s1lo[o] = f2bf(v - bf2f(h));
        }
        return;
    }
    const float* in = (z == 0) ? W0 : (z == 1) ? W1 : (z == 2) ? W2 : W3;
    ushort_t*   out = (z == 0) ? O0 : (z == 1) ? O1 : (z == 2) ? O2 : O3;
    const float scale = (z == 0) ? 0.125f : 1.0f;  // fold HD^-0.5 into Wq (exact)
#pragma unroll
    for (int i = 0; i < 32; i += 8)
        tile[ty + i][tx] = in[(long)(r0 + ty + i) * 512 + c0 + tx];
    __syncthreads();
#pragma unroll
    for (int i = 0; i < 32; i += 8)
        out[(long)(c0 + ty + i) * 512 + r0 + tx] = f2bf(tile[tx][ty + i] * scale);
}

// ---------------------------------------------------------------------------
// imp via hi/lo bf16 MFMA (error ~1e-5 vs fp32, << top-k spacing):
// h = xhi@Whi + xhi@Wlo + xlo@Whi + bs1 (fp32 acc); imp = gelu(h) @ Ws2.
// v2 (verified r9): 256-thread blocks; wave = 32 tok x 64 j.
// ---------------------------------------------------------------------------
__global__ __launch_bounds__(256) void imp_mfma_k(
    const ushort_t* __restrict__ xhi, const ushort_t* __restrict__ xlo,
    const ushort_t* __restrict__ w1hi, const ushort_t* __restrict__ w1lo,
    const float* __restrict__ bs1, const float* __restrict__ Ws2,
    float* __restrict__ imp)
{
    __shared__ float red[4][32];
    const int tid = threadIdx.x, lane = tid & 63, w = tid >> 6;
    const int l15 = lane & 15, l4 = lane >> 4;
    const int tok0 = blockIdx.x * 32;
    const int j0 = w * 64;

    const ushort_t* a0h = xhi + (long)(tok0 + l15) * 512 + l4 * 8;
    const ushort_t* a1h = a0h + 16 * 512;
    const ushort_t* a0l = xlo + (long)(tok0 + l15) * 512 + l4 * 8;
    const ushort_t* a1l = a0l + 16 * 512;
    const ushort_t* bh0 = w1hi + (long)(j0 + l15) * 512 + l4 * 8;
    const ushort_t* bl0 = w1lo + (long)(j0 + l15) * 512 + l4 * 8;

    f32x4 acc[2][4];
#pragma unroll
    for (int c = 0; c < 4; ++c) {
        const float bv = bs1[j0 + c * 16 + l15];
#pragma unroll
        for (int g = 0; g < 2; ++g)
#pragma unroll
            for (int r = 0; r < 4; ++r) acc[g][c][r] = bv;
    }

#pragma unroll 2
    for (int kk = 0; kk < 16; ++kk) {
        const int ko = kk * 32;
        const short8 A0 = *(const short8*)(a0h + ko);
        const short8 A1 = *(const short8*)(a1h + ko);
        const short8 L0 = *(const short8*)(a0l + ko);
        const short8 L1 = *(const short8*)(a1l + ko);
#pragma unroll
        for (int c = 0; c < 4; ++c) {
            const short8 Bh = *(const short8*)(bh0 + c * (16 * 512) + ko);
            const short8 Bl = *(const short8*)(bl0 + c * (16 * 512) + ko);
            acc[0][c] = __builtin_amdgcn_mfma_f32_16x16x32_bf16(A0, Bh, acc[0][c], 0, 0, 0);
            acc[1][c] = __builtin_amdgcn_mfma_f32_16x16x32_bf16(A1, Bh, acc[1][c], 0, 0, 0);
            acc[0][c] = __builtin_amdgcn_mfma_f32_16x16x32_bf16(A0, Bl, acc[0][c], 0, 0, 0);
            acc[1][c] = __builtin_amdgcn_mfma_f32_16x16x32_bf16(A1, Bl, acc[1][c], 0, 0, 0);
            acc[0][c] = __builtin_amdgcn_mfma_f32_16x16x32_bf16(L0, Bh, acc[0][c], 0, 0, 0);
            acc[1][c] = __builtin_amdgcn_mfma_f32_16x16x32_bf16(L1, Bh, acc[1][c], 0, 0, 0);
        }
    }

    float ws2c[4];
#pragma unroll
    for (int c = 0; c < 4; ++c) ws2c[c] = Ws2[j0 + c * 16 + l15];
#pragma unroll
    for (int g = 0; g < 2; ++g)
#pragma unroll
        for (int r = 0; r < 4; ++r) {
            float p = 0.0f;
#pragma unroll
            for (int c = 0; c < 4; ++c) {
                const float hv = acc[g][c][r];
                p = fmaf(0.5f * hv * (1.0f + erff(hv * 0.70710678118f)), ws2c[c], p);
            }
            p += __shfl_xor(p, 1); p += __shfl_xor(p, 2);
            p += __shfl_xor(p, 4); p += __shfl_xor(p, 8);
            if (l15 == 0) red[w][g * 16 + l4 * 4 + r] = p;
        }
    __syncthreads();
    if (tid < 32)
        imp[tok0 + tid] = (red[0][tid] + red[1][tid]) + (red[2][tid] + red[3][tid]);
}

// ---------------------------------------------------------------------------
// Per-batch exact top-k via radix-select, then index-ordered tie resolution
// (matches jax.lax.top_k selected SET). One block (1024 thr) per batch.
// ---------------------------------------------------------------------------
__global__ __launch_bounds__(1024) void topk_select_k(
    const float* __restrict__ imp, unsigned char* __restrict__ sel)
{
    __shared__ unsigned int keys[4096];
    __shared__ unsigned int hist[256];
    __shared__ int chunkscan[64];
    __shared__ unsigned int sh_prefix;
    __shared__ int sh_rem;
    const int b = blockIdx.x, tid = threadIdx.x;
    const int lane = tid & 63, w = tid >> 6;
    for (int i = tid; i < 4096; i += 1024) {
        const unsigned int u = __float_as_uint(imp[b * 4096 + i]);
        keys[i] = (u & 0x80000000u) ? ~u : (u | 0x80000000u);  // order-preserving
    }
    if (tid == 0) { sh_prefix = 0u; sh_rem = TOPK_; }
    __syncthreads();
    unsigned int pmask = 0;
    for (int level = 3; level >= 0; --level) {
        const int shb = level * 8;
        const unsigned int prefix = sh_prefix;
        const int remaining = sh_rem;
        if (tid < 256) hist[tid] = 0;
        __syncthreads();
        for (int i = tid; i < 4096; i += 1024) {
            const unsigned int u = keys[i];
            if ((u & pmask) == prefix) atomicAdd(&hist[(u >> shb) & 255u], 1u);
        }
        __syncthreads();
        if (tid < 64) {
            unsigned int v[4];
            int tot = 0;
#pragma unroll
            for (int q = 0; q < 4; ++q) { v[q] = hist[255 - (tid * 4 + q)]; tot += (int)v[q]; }
            int pre = tot;
            for (int off = 1; off < 64; off <<= 1) {
                const int t = __shfl_up(pre, off);
                if (tid >= off) pre += t;
            }
            const unsigned long long bal = __ballot(pre >= remaining);
            const int L = __ffsll((unsigned long long)bal) - 1;
            if (tid == L) {
                int c = pre - tot;
#pragma unroll
                for (int q = 0; q < 4; ++q) {
                    c += (int)v[q];
                    if (c >= remaining) {
                        sh_rem = remaining - (c - (int)v[q]);
                        sh_prefix = prefix | ((unsigned int)(255 - (tid * 4 + q)) << shb);
                        break;
                    }
                }
            }
        }
        __syncthreads();
        pmask |= (255u << shb);
    }
    const unsigned int T = sh_prefix;
    const int need = sh_rem;  // how many == T elements to take (index asc)
#pragma unroll
    for (int q = 0; q < 4; ++q) {
        const int chunk = w * 4 + q;
        const unsigned long long bal = __ballot(keys[chunk * 64 + lane] == T);
        if (lane == 0) chunkscan[chunk] = __popcll(bal);
    }
    __syncthreads();
    if (tid < 64) {
        const int v = chunkscan[tid];
        int pre = v;
        for (int off = 1; off < 64; off <<= 1) {
            const int t = __shfl_up(pre, off);
            if (tid >= off) pre += t;
        }
        chunkscan[tid] = pre - v;  // exclusive prefix
    }
    __syncthreads();
#pragma unroll
    for (int q = 0; q < 4; ++q) {
        const int chunk = w * 4 + q;
        const int i = chunk * 64 + lane;
        const unsigned int u = keys[i];
        const bool eq = (u == T);
        const unsigned long long bal = __ballot(eq);
        const int rank = chunkscan[chunk] + __popcll(bal & ((1ull << lane) - 1ull));
        sel[b * 4096 + i] = (u > T || (eq && rank < need)) ? 1 : 0;
    }
}

// ---------------------------------------------------------------------------
// Union of selections -> compacted ascending column list + gather rowmap.
// Lane-parallel: lane i owns tokens i*64..i*64+63 (bitmask + shfl scan).
// ---------------------------------------------------------------------------
__global__ void compact_k(const unsigned char* __restrict__ sel,
                          int* __restrict__ rowmap, int* __restrict__ keffp)
{
    const int lane = threadIdx.x;  // 64 threads = 1 wave
    const unsigned long long* p0 = (const unsigned long long*)(sel);
    const unsigned long long* p1 = (const unsigned long long*)(sel + 4096);
    unsigned long long bits = 0;
#pragma unroll
    for (int q = 0; q < 8; ++q) {
        const unsigned long long u = p0[lane * 8 + q] | p1[lane * 8 + q];
        unsigned long long b8 = 0;
#pragma unroll
        for (int j = 0; j < 8; ++j) b8 |= ((u >> (8 * j)) & 1ull) << j;
        bits |= b8 << (8 * q);
    }
    const int cnt = __popcll(bits);
    int pre = cnt;
    for (int off = 1; off < 64; off <<= 1) {
        const int t = __shfl_up(pre, off);
        if (lane >= off) pre += t;
    }
    const int total = __shfl(pre, 63);
    int ofs = pre - cnt;  // exclusive prefix
    unsigned long long m = bits;
    while (m) {
        const int j = __ffsll(m) - 1;
        const int pos = lane * 64 + j;
        rowmap[ofs] = pos;                  // batch 0 token row
        rowmap[KSLOTS_ + ofs] = 4096 + pos; // batch 1 token row
        ++ofs;
        m &= m - 1;
    }
    for (int s = total + lane; s < KSLOTS_; s += 64) {
        rowmap[s] = 0; rowmap[KSLOTS_ + s] = 4096;  // pad -> token 0 (masked)
    }
    if (lane == 0) keffp[0] = total;
}

// ---------------------------------------------------------------------------
// Merged K-proj + V^T-proj (one launch, flat grid of 128 blocks).
//  id < 64:  k_sel[s][512] = xb[rowmap[s]] @ Wk + bk     (M=1024, tiles 8x8)
//  id >= 64: vT[d][col]   = Wv^T[d] . xb[rowmap[vperm(col)]] + bv[d]
// ---------------------------------------------------------------------------
__global__ __launch_bounds__(256) void gemm_kv_k(
    const ushort_t* __restrict__ xb,
    const ushort_t* __restrict__ WkT, const float* __restrict__ bk,
    ushort_t* __restrict__ k_sel,
    const ushort_t* __restrict__ WvT, const float* __restrict__ bv,
    ushort_t* __restrict__ vT, const int* __restrict__ rowmap)
{
    const int K = 512;
    const int tid = threadIdx.x, lane = tid & 63, w = tid >> 6;
    const int l15 = lane & 15, l4 = lane >> 4;
    const int id = blockIdx.x;

    if (id < 64) {
        const int m_base = (id & 7) * 128 + w * 32;
        const int n_base = (id >> 3) * 64;
        const long ar0 = (long)rowmap[m_base + l15];
        const long ar1 = (long)rowmap[m_base + 16 + l15];
        const ushort_t* a0p = xb + ar0 * K + l4 * 8;
        const ushort_t* a1p = xb + ar1 * K + l4 * 8;
        const ushort_t* bp0 = WkT + (long)(n_base +  0 + l15) * K + l4 * 8;
        const ushort_t* bp1 = WkT + (long)(n_base + 16 + l15) * K + l4 * 8;
        const ushort_t* bp2 = WkT + (long)(n_base + 32 + l15) * K + l4 * 8;
        const ushort_t* bp3 = WkT + (long)(n_base + 48 + l15) * K + l4 * 8;
        f32x4 acc[2][4] = {};
#pragma unroll 4
        for (int kk = 0; kk < 16; ++kk) {
            const int ko = kk * 32;
            const short8 a0 = *(const short8*)(a0p + ko);
            const short8 a1 = *(const short8*)(a1p + ko);
            const short8 b0 = *(const short8*)(bp0 + ko);
            const short8 b1 = *(const short8*)(bp1 + ko);
            const short8 b2 = *(const short8*)(bp2 + ko);
            const short8 b3 = *(const short8*)(bp3 + ko);
            acc[0][0] = __builtin_amdgcn_mfma_f32_16x16x32_bf16(a0, b0, acc[0][0], 0, 0, 0);
            acc[1][0] = __builtin_amdgcn_mfma_f32_16x16x32_bf16(a1, b0, acc[1][0], 0, 0, 0);
            acc[0][1] = __builtin_amdgcn_mfma_f32_16x16x32_bf16(a0, b1, acc[0][1], 0, 0, 0);
            acc[1][1] = __builtin_amdgcn_mfma_f32_16x16x32_bf16(a1, b1, acc[1][1], 0, 0, 0);
            acc[0][2] = __builtin_amdgcn_mfma_f32_16x16x32_bf16(a0, b2, acc[0][2], 0, 0, 0);
            acc[1][2] = __builtin_amdgcn_mfma_f32_16x16x32_bf16(a1, b2, acc[1][2], 0, 0, 0);
            acc[0][3] = __builtin_amdgcn_mfma_f32_16x16x32_bf16(a0, b3, acc[0][3], 0, 0, 0);
            acc[1][3] = __builtin_amdgcn_mfma_f32_16x16x32_bf16(a1, b3, acc[1][3], 0, 0, 0);
        }
#pragma unroll
        for (int g = 0; g < 2; ++g)
#pragma unroll
            for (int c = 0; c < 4; ++c) {
                const int col = n_base + c * 16 + l15;
                const float bvv = bk[col];
#pragma unroll
                for (int r = 0; r < 4; ++r) {
                    const int row = m_base + g * 16 + l4 * 4 + r;
                    k_sel[(long)row * 512 + col] = f2bf(acc[g][c][r] + bvv);
                }
            }
    } else {
        const int vid = id - 64;
        const int m_base = (vid & 3) * 128 + w * 32;   // d
        const int n_base = (vid >> 2) * 64;            // b*512+slot (physical)
        const ushort_t* a0p = WvT + (long)(m_base + l15) * K + l4 * 8;
        const ushort_t* a1p = WvT + (long)(m_base + 16 + l15) * K + l4 * 8;
        const long c0 = rowmap[vperm(n_base +  0 + l15)];
        const long c1 = rowmap[vperm(n_base + 16 + l15)];
        const long c2 = rowmap[vperm(n_base + 32 + l15)];
        const long c3 = rowmap[vperm(n_base + 48 + l15)];
        const ushort_t* bp0 = xb + c0 * K + l4 * 8;
        const ushort_t* bp1 = xb + c1 * K + l4 * 8;
        const ushort_t* bp2 = xb + c2 * K + l4 * 8;
        const ushort_t* bp3 = xb + c3 * K + l4 * 8;
        f32x4 acc[2][4] = {};
#pragma unroll 4
        for (int kk = 0; kk < 16; ++kk) {
            const int ko = kk * 32;
            const short8 a0 = *(const short8*)(a0p + ko);
            const short8 a1 = *(const short8*)(a1p + ko);
            const short8 b0 = *(const short8*)(bp0 + ko);
            const short8 b1 = *(const short8*)(bp1 + ko);
            const short8 b2 = *(const short8*)(bp2 + ko);
            const short8 b3 = *(const short8*)(bp3 + ko);
            acc[0][0] = __builtin_amdgcn_mfma_f32_16x16x32_bf16(a0, b0, acc[0][0], 0, 0, 0);
            acc[1][0] = __builtin_amdgcn_mfma_f32_16x16x32_bf16(a1, b0, acc[1][0], 0, 0, 0);
            acc[0][1] = __builtin_amdgcn_mfma_f32_16x16x32_bf16(a0, b1, acc[0][1], 0, 0, 0);
            acc[1][1] = __builtin_amdgcn_mfma_f32_16x16x32_bf16(a1, b1, acc[1][1], 0, 0, 0);
            acc[0][2] = __builtin_amdgcn_mfma_f32_16x16x32_bf16(a0, b2, acc[0][2], 0, 0, 0);
            acc[1][2] = __builtin_amdgcn_mfma_f32_16x16x32_bf16(a1, b2, acc[1][2], 0, 0, 0);
            acc[0][3] = __builtin_amdgcn_mfma_f32_16x16x32_bf16(a0, b3, acc[0][3], 0, 0, 0);
            acc[1][3] = __builtin_amdgcn_mfma_f32_16x16x32_bf16(a1, b3, acc[1][3], 0, 0, 0);
        }
#pragma unroll
        for (int g = 0; g < 2; ++g)
#pragma unroll
            for (int r = 0; r < 4; ++r) {
                const int row = m_base + g * 16 + l4 * 4 + r;  // d
                const float bvv = bv[row];
#pragma unroll
                for (int c = 0; c < 4; ++c) {
                    const int col = n_base + c * 16 + l15;
                    vT[(long)row * 1024 + col] = f2bf(acc[g][c][r] + bvv);
                }
            }
    }
}

// ---------------------------------------------------------------------------
// LDS-staged GEMM (verified r8/r9 single-buffer): C = A @ W + bias*bscale.
// Tile 128x64, BK=64. global_load_lds width=16 with T2 XOR swizzle
// (pre-swizzled global source + swizzled ds_read — both-sides rule #21).
// ---------------------------------------------------------------------------
__global__ __launch_bounds__(256) void gemm128_k(
    const ushort_t* __restrict__ A, const ushort_t* __restrict__ WT,
    const float* __restrict__ bias, float bscale,
    ushort_t* __restrict__ Cb, float* __restrict__ Cf)
{
    __shared__ __align__(16) ushort_t Al[128 * 64];
    __shared__ __align__(16) ushort_t Bl[64 * 64];
    const int tid = threadIdx.x, lane = tid & 63, w = tid >> 6;
    const int l15 = lane & 15, l4 = lane >> 4;
    const int m0 = blockIdx.x * 128, n0 = blockIdx.y * 64;
    const int row_off = lane >> 3, kq = lane & 7;      // staging lane roles
    const int src_k8 = (kq ^ row_off) * 8;             // inverse-swizzled source

    f32x4 acc[2][4] = {};
#pragma unroll 1
    for (int kt = 0; kt < 8; ++kt) {
        __syncthreads();  // all waves done reading previous tile
#pragma unroll
        for (int i = 0; i < 4; ++i) {
            const int ia = w * 4 + i;
            const long ga = (long)(m0 + ia * 8 + row_off) * 512 + kt * 64 + src_k8;
            __builtin_amdgcn_global_load_lds((const g_u32*)(A + ga),
                                             (l_u32*)(Al + ia * 512), 16, 0, 0);
        }
#pragma unroll
        for (int i = 0; i < 2; ++i) {
            const int ib = w * 2 + i;
            const long gb = (long)(n0 + ib * 8 + row_off) * 512 + kt * 64 + src_k8;
            __builtin_amdgcn_global_load_lds((const g_u32*)(WT + gb),
                                             (l_u32*)(Bl + ib * 512), 16, 0, 0);
        }
        __syncthreads();  // tile ready (compiler drains vmcnt before barrier)
#pragma unroll
        for (int kh = 0; kh < 2; ++kh) {
            short8 af[2], bfr[4];
#pragma unroll
            for (int t = 0; t < 2; ++t) {
                const int row = w * 32 + t * 16 + l15;
                const int c8 = (kh * 4 + l4) ^ (row & 7);
                af[t] = *(const short8*)(Al + row * 64 + c8 * 8);
            }
#pragma unroll
            for (int u = 0; u < 4; ++u) {
                const int col = u * 16 + l15;
                const int c8 = (kh * 4 + l4) ^ (col & 7);
                bfr[u] = *(const short8*)(Bl + col * 64 + c8 * 8);
            }
#pragma unroll
            for (int t = 0; t < 2; ++t)
#pragma unroll
                for (int u = 0; u < 4; ++u)
                    acc[t][u] = __builtin_amdgcn_mfma_f32_16x16x32_bf16(
                        af[t], bfr[u], acc[t][u], 0, 0, 0);
        }
    }
#pragma unroll
    for (int t = 0; t < 2; ++t)
#pragma unroll
        for (int u = 0; u < 4; ++u) {
            const int col = n0 + u * 16 + l15;
            const float bv = bias[col] * bscale;
#pragma unroll
            for (int r = 0; r < 4; ++r) {
                const int row = m0 + w * 32 + t * 16 + l4 * 4 + r;
                const float val = acc[t][u][r] + bv;
                if (Cf) Cf[(long)row * 512 + col] = val;
                else    Cb[(long)row * 512 + col] = f2bf(val);
            }
        }
}

// ---------------------------------------------------------------------------
// Flash attention v5 (verified r9): swapped QK^T (q lane-local) +
// pre-permuted V => P never leaves registers (zero LDS). cvt_pk packs P to
// bf16 A-fragments. Grid = B*H*(S/128) = 512 blocks; 4 waves x 32 q-rows.
// Q pre-scaled by HD^-0.5.
// ---------------------------------------------------------------------------
__global__ __launch_bounds__(256) void attn_k(
    const ushort_t* __restrict__ q_all, const ushort_t* __restrict__ k_sel,
    const ushort_t* __restrict__ vT, const int* __restrict__ keff_p,
    ushort_t* __restrict__ att)
{
    const int tid = threadIdx.x;
    const int lane = tid & 63, w = tid >> 6;
    const int l15 = lane & 15, l4 = lane >> 4;
    const int bidx = blockIdx.x;
    const int qt = bidx & 31, h = (bidx >> 5) & 7, b = bidx >> 8;
    const int q0 = qt * 128;
    const int keff = keff_p[0];
    const int nfull = keff >> 6;
    const int ntiles = (keff + 63) >> 6;

    // Q fragments (B operand; input col = q = l15)
    short8 qf[2][2];
#pragma unroll
    for (int g = 0; g < 2; ++g) {
        const ushort_t* qrow =
            q_all + (long)(b * 4096 + q0 + w * 32 + g * 16 + l15) * 512 + h * 64;
#pragma unroll
        for (int ks = 0; ks < 2; ++ks)
            qf[g][ks] = *(const short8*)(qrow + ks * 32 + l4 * 8);
    }

    f32x4 acc[2][4] = {};
    float mrun[2] = {-3.0e38f, -3.0e38f};
    float lrun[2] = {0.0f, 0.0f};

#pragma unroll 1
    for (int t = 0; t < ntiles; ++t) {
        // ---- swapped scores: D[key][q], q = l15, key = c*16 + l4*4 + r ----
        f32x4 s[2][4] = {};
#pragma unroll
        for (int c = 0; c < 4; ++c) {
            const ushort_t* krow =
                k_sel + (long)(b * KSLOTS_ + t * 64 + c * 16 + l15) * 512 + h * 64;
#pragma unroll
            for (int ks = 0; ks < 2; ++ks) {
                const short8 kf = *(const short8*)(krow + ks * 32 + l4 * 8);
                s[0][c] = __builtin_amdgcn_mfma_f32_16x16x32_bf16(kf, qf[0][ks], s[0][c], 0, 0, 0);
                s[1][c] = __builtin_amdgcn_mfma_f32_16x16x32_bf16(kf, qf[1][ks], s[1][c], 0, 0, 0);
            }
        }
        // ---- pad mask (stored-row coords), partial tile only ----
        if (t >= nfull) {
            const int rbase = t * 64 + l4 * 4;
#pragma unroll
            for (int c = 0; c < 4; ++c)
#pragma unroll
                for (int r = 0; r < 4; ++r) {
                    const bool valid = (rbase + c * 16 + r) < keff;
                    s[0][c][r] = valid ? s[0][c][r] : -1.0e30f;
                    s[1][c][r] = valid ? s[1][c][r] : -1.0e30f;
                }
        }
        // ---- per-thread row stats (all 16 values share q = l15) ----
        float mn[2];
        bool chg = false;
#pragma unroll
        for (int g = 0; g < 2; ++g) {
            float rm = -3.0e38f;
#pragma unroll
            for (int c = 0; c < 4; ++c)
                rm = fmaxf(rm, fmaxf(fmaxf(s[g][c][0], s[g][c][1]),
                                     fmaxf(s[g][c][2], s[g][c][3])));
            rm = fmaxf(rm, __shfl_xor(rm, 16));
            rm = fmaxf(rm, __shfl_xor(rm, 32));
            mn[g] = (rm > mrun[g] + 8.0f) ? rm : mrun[g];  // defer-max THR=8
            chg |= (mn[g] != mrun[g]);
        }
        if (__any(chg)) {
#pragma unroll
            for (int g = 0; g < 2; ++g) {
                const float sc = __expf(mrun[g] - mn[g]);
                lrun[g] *= sc;
#pragma unroll
                for (int r = 0; r < 4; ++r) {
                    const float scr = __shfl(sc, l4 * 4 + r);  // q of acc row r
#pragma unroll
                    for (int cd = 0; cd < 4; ++cd) acc[g][cd][r] *= scr;
                }
            }
        }
        mrun[0] = mn[0]; mrun[1] = mn[1];
#pragma unroll
        for (int g = 0; g < 2; ++g) {
            float rs = 0.0f;
#pragma unroll
            for (int c = 0; c < 4; ++c)
#pragma unroll
                for (int r = 0; r < 4; ++r) {
                    const float e = __expf(s[g][c][r] - mrun[g]);
                    s[g][c][r] = e;
                    rs += e;
                }
            rs += __shfl_xor(rs, 16);
            rs += __shfl_xor(rs, 32);
            lrun[g] += rs;
        }
        // ---- pack P into bf16 A-fragments (register-only; V pre-permuted) ----
        short8 pf[2][2];
#pragma unroll
        for (int g = 0; g < 2; ++g)
#pragma unroll
            for (int ks = 0; ks < 2; ++ks) {
                union { unsigned int u[4]; short8 v; } uu;
                asm("v_cvt_pk_bf16_f32 %0, %1, %2"
                    : "=v"(uu.u[0]) : "v"(s[g][2 * ks][0]), "v"(s[g][2 * ks][1]));
                asm("v_cvt_pk_bf16_f32 %0, %1, %2"
                    : "=v"(uu.u[1]) : "v"(s[g][2 * ks][2]), "v"(s[g][2 * ks][3]));
                asm("v_cvt_pk_bf16_f32 %0, %1, %2"
                    : "=v"(uu.u[2]) : "v"(s[g][2 * ks + 1][0]), "v"(s[g][2 * ks + 1][1]));
                asm("v_cvt_pk_bf16_f32 %0, %1, %2"
                    : "=v"(uu.u[3]) : "v"(s[g][2 * ks + 1][2]), "v"(s[g][2 * ks + 1][3]));
                pf[g][ks] = uu.v;
            }
        // ---- PV: O += P @ V ----
#pragma unroll
        for (int cd = 0; cd < 4; ++cd) {
            const ushort_t* vrow =
                vT + (long)(h * 64 + cd * 16 + l15) * 1024 + b * 512 + t * 64;
#pragma unroll
            for (int ks = 0; ks < 2; ++ks) {
                const short8 vf = *(const short8*)(vrow + ks * 32 + l4 * 8);
                acc[0][cd] = __builtin_amdgcn_mfma_f32_16x16x32_bf16(pf[0][ks], vf, acc[0][cd], 0, 0, 0);
                acc[1][cd] = __builtin_amdgcn_mfma_f32_16x16x32_bf16(pf[1][ks], vf, acc[1][cd], 0, 0, 0);
            }
        }
    }
    // ---- normalize + store: acc row r has q = l4*4 + r ----
#pragma unroll
    for (int g = 0; g < 2; ++g)
#pragma unroll
        for (int r = 0; r < 4; ++r) {
            const float lr = __shfl(lrun[g], l4 * 4 + r);
            const float inv = 1.0f / lr;
            const int row = q0 + w * 32 + g * 16 + l4 * 4 + r;
#pragma unroll
            for (int cd = 0; cd < 4; ++cd)
                att[(long)(b * 4096 + row) * 512 + h * 64 + cd * 16 + l15] =
                    f2bf(acc[g][cd][r] * inv);
        }
}

// ---------------------------------------------------------------------------
extern "C" void kernel_launch(void* const* d_in, const int* in_sizes, int n_in,
                              void* d_out, int out_size, void* d_ws, size_t ws_size,
                              hipStream_t stream)
{
    const float* x   = (const float*)d_in[0];
    const float* Wq  = (const float*)d_in[1];
    const float* bq  = (const float*)d_in[2];
    const float* Wk  = (const float*)d_in[3];
    const float* bk  = (const float*)d_in[4];
    const float* Wv  = (const float*)d_in[5];
    const float* bv  = (const float*)d_in[6];
    const float* Wo  = (const float*)d_in[7];
    const float* bo  = (const float*)d_in[8];
    const float* Ws1 = (const float*)d_in[9];
    const float* bs1 = (const float*)d_in[10];
    const float* Ws2 = (const float*)d_in[11];
    // d_in[12] = bs2 (selection-invariant, unused), d_in[13] = top_k (=256)

    char* ws = (char*)d_ws;
    float*          imp    = (float*)(ws + 0);              // 32 KB
    unsigned char*  sel    = (unsigned char*)(ws + 0x8000); // 8 KB
    int*            keffp  = (int*)(ws + 0xA800);
    int*            rowmap = (int*)(ws + 0xB000);           // 4 KB
    ushort_t*  WqT    = (ushort_t*)(ws + 0x40000);          // 4 x 512 KB
    ushort_t*  WkT    = WqT + 512 * 512;
    ushort_t*  WvT    = WkT + 512 * 512;
    ushort_t*  WoT    = WvT + 512 * 512;
    ushort_t*  k_sel  = (ushort_t*)(ws + 0x240000);         // 1 MB
    ushort_t*  vT     = (ushort_t*)(ws + 0x340000);         // 1 MB
    ushort_t*  w1hi   = (ushort_t*)(ws + 0x440000);         // 256 KB
    ushort_t*  w1lo   = (ushort_t*)(ws + 0x480000);         // 256 KB
    ushort_t*  xb     = (ushort_t*)(ws + 0x600000);         // 8 MB (= x_hi; reused as att)
    ushort_t*  att    = xb;                                 // dead after projections
    ushort_t*  xlo    = (ushort_t*)(ws + 0xE00000);         // 8 MB (reused as q_all)
    ushort_t*  q_all  = xlo;                                // xlo dead after imp_mfma

    const dim3 tblk(256);
    // 1. fused prep: x hi/lo pack + all weight transposes (Wq scaled 0.125)
    prep_k<<<3328, tblk, 0, stream>>>(x, xb, xlo, Wq, Wk, Wv, Wo, Ws1,
                                      WqT, WkT, WvT, WoT, w1hi, w1lo);
    // 2. importance via hi/lo MFMA (selection-exact vs fp32)
    imp_mfma_k<<<256, tblk, 0, stream>>>(xb, xlo, w1hi, w1lo, bs1, Ws2, imp);
    // 3. per-batch top-k via radix select
    topk_select_k<<<2, 1024, 0, stream>>>(imp, sel);
    // 4. union mask -> compacted column list + gather map (lane-parallel)
    compact_k<<<1, 64, 0, stream>>>(sel, rowmap, keffp);
    // 5. projections: LDS-staged dense Q (0.125-scaled; overwrites xlo — dead),
    //    merged gathered K + permuted V^T
    gemm128_k<<<dim3(64, 8), tblk, 0, stream>>>(xb, WqT, bq, 0.125f, q_all, nullptr);
    gemm_kv_k<<<128, tblk, 0, stream>>>(xb, WkT, bk, k_sel, WvT, bv, vT, rowmap);
    // 6. sparse flash attention v5 (att overwrites xb region — xb is dead now)
    attn_k<<<512, tblk, 0, stream>>>(q_all, k_sel, vT, keffp, att);
    // 7. output projection (LDS-staged) -> d_out (fp32)
    gemm128_k<<<dim3(64, 8), tblk, 0, stream>>>(att, WoT, bo, 1.0f, nullptr, (float*)d_out);
}

// Round 15
// 117.882 us; speedup vs baseline: 1.1289x; 1.0574x over previous
//
#include <hip/hip_runtime.h>
#include <hip/hip_bf16.h>

typedef unsigned short ushort_t;
typedef short short8 __attribute__((ext_vector_type(8)));
typedef float f32x4 __attribute__((ext_vector_type(4)));

#define B_  2
#define S_  4096
#define D_  512
#define H_  8
#define HD_ 64
#define DK_ 256
#define TOPK_ 256
#define KSLOTS_ 512   // 2*TOPK_ slots (union of both batches' top-k)

typedef __attribute__((address_space(1))) unsigned int g_u32;
typedef __attribute__((address_space(3))) unsigned int l_u32;

__device__ __forceinline__ float bf2f(ushort_t u) {
    unsigned int b = ((unsigned int)u) << 16;
    float f;
    __builtin_memcpy(&f, &b, 4);
    return f;
}
__device__ __forceinline__ ushort_t f2bf(float f) {
    unsigned int b;
    __builtin_memcpy(&b, &f, 4);
    b = (b + 0x7FFFu + ((b >> 16) & 1u)) >> 16;
    return (ushort_t)b;
}

// V column permutation: physical PV slot p <- stored K row s(p).
// Makes swapped-QK P register layout == MFMA A-fragment layout.
__device__ __forceinline__ int vperm(int p) {
    const int hi = p & ~63, p64 = p & 63;
    const int ks = p64 >> 5, a = (p64 >> 3) & 3, j = p64 & 7;
    return hi | ((2 * ks + (j >> 2)) * 16 + a * 4 + (j & 3));
}

// ---------------------------------------------------------------------------
// Fused prep: flat grid.
//  blocks [0, 2048):    x fp32 -> bf16 hi/lo pack (8 elem/thread)
//  blocks [2048, 3328): weight transposes fp32 -> bf16
//     z=0..3: Wq/Wk/Wv/Wo 512x512 -> W^T (z==0 pre-scaled by 0.125)
//     z=4:    Ws1 512x256 -> Ws1^T hi/lo
// ---------------------------------------------------------------------------
__global__ __launch_bounds__(256) void prep_k(
    const float* __restrict__ x, ushort_t* __restrict__ xhi,
    ushort_t* __restrict__ xlo,
    const float* __restrict__ W0, const float* __restrict__ W1,
    const float* __restrict__ W2, const float* __restrict__ W3,
    const float* __restrict__ Ws1,
    ushort_t* __restrict__ O0, ushort_t* __restrict__ O1,
    ushort_t* __restrict__ O2, ushort_t* __restrict__ O3,
    ushort_t* __restrict__ s1hi, ushort_t* __restrict__ s1lo)
{
    if (blockIdx.x < 2048) {
        const long i = ((long)blockIdx.x * 256 + threadIdx.x) * 8;
        const float4 a = *(const float4*)(x + i);
        const float4 b = *(const float4*)(x + i + 4);
        float v[8] = {a.x, a.y, a.z, a.w, b.x, b.y, b.z, b.w};
        short8 oh, ol;
#pragma unroll
        for (int q = 0; q < 8; ++q) {
            const ushort_t h = f2bf(v[q]);
            oh[q] = (short)h;
            ol[q] = (short)f2bf(v[q] - bf2f(h));
        }
        *(short8*)(xhi + i) = oh;
        *(short8*)(xlo + i) = ol;
        return;
    }
    __shared__ float tile[32][33];
    const int idx = blockIdx.x - 2048;
    const int z = idx >> 8, rem = idx & 255;
    const int bx = rem & 15, by = rem >> 4;
    const int tx = threadIdx.x & 31, ty = threadIdx.x >> 5;  // 32 x 8
    const int c0 = bx * 32, r0 = by * 32;
    if (z == 4) {
        if (bx >= 8) return;  // Ws1 is 512x256
#pragma unroll
        for (int i = 0; i < 32; i += 8)
            tile[ty + i][tx] = Ws1[(long)(r0 + ty + i) * 256 + c0 + tx];
        __syncthreads();
#pragma unroll
        for (int i = 0; i < 32; i += 8) {
            const float v = tile[tx][ty + i];
            const ushort_t h = f2bf(v);
            const long o = (long)(c0 + ty + i) * 512 + r0 + tx;
            s1hi[o] = h;
            s1lo[o] = f2bf(v - bf2f(h));
        }
        return;
    }
    const float* in = (z == 0) ? W0 : (z == 1) ? W1 : (z == 2) ? W2 : W3;
    ushort_t*   out = (z == 0) ? O0 : (z == 1) ? O1 : (z == 2) ? O2 : O3;
    const float scale = (z == 0) ? 0.125f : 1.0f;  // fold HD^-0.5 into Wq (exact)
#pragma unroll
    for (int i = 0; i < 32; i += 8)
        tile[ty + i][tx] = in[(long)(r0 + ty + i) * 512 + c0 + tx];
    __syncthreads();
#pragma unroll
    for (int i = 0; i < 32; i += 8)
        out[(long)(c0 + ty + i) * 512 + r0 + tx] = f2bf(tile[tx][ty + i] * scale);
}

// ---------------------------------------------------------------------------
// imp via hi/lo bf16 MFMA (error ~1e-5 vs fp32, << top-k spacing):
// h = xhi@Whi + xhi@Wlo + xlo@Whi + bs1 (fp32 acc); imp = gelu(h) @ Ws2.
// v2 (verified r9/r14): 256-thread blocks; wave = 32 tok x 64 j.
// ---------------------------------------------------------------------------
__global__ __launch_bounds__(256) void imp_mfma_k(
    const ushort_t* __restrict__ xhi, const ushort_t* __restrict__ xlo,
    const ushort_t* __restrict__ w1hi, const ushort_t* __restrict__ w1lo,
    const float* __restrict__ bs1, const float* __restrict__ Ws2,
    float* __restrict__ imp)
{
    __shared__ float red[4][32];
    const int tid = threadIdx.x, lane = tid & 63, w = tid >> 6;
    const int l15 = lane & 15, l4 = lane >> 4;
    const int tok0 = blockIdx.x * 32;
    const int j0 = w * 64;

    const ushort_t* a0h = xhi + (long)(tok0 + l15) * 512 + l4 * 8;
    const ushort_t* a1h = a0h + 16 * 512;
    const ushort_t* a0l = xlo + (long)(tok0 + l15) * 512 + l4 * 8;
    const ushort_t* a1l = a0l + 16 * 512;
    const ushort_t* bh0 = w1hi + (long)(j0 + l15) * 512 + l4 * 8;
    const ushort_t* bl0 = w1lo + (long)(j0 + l15) * 512 + l4 * 8;

    f32x4 acc[2][4];
#pragma unroll
    for (int c = 0; c < 4; ++c) {
        const float bv = bs1[j0 + c * 16 + l15];
#pragma unroll
        for (int g = 0; g < 2; ++g)
#pragma unroll
            for (int r = 0; r < 4; ++r) acc[g][c][r] = bv;
    }

#pragma unroll 2
    for (int kk = 0; kk < 16; ++kk) {
        const int ko = kk * 32;
        const short8 A0 = *(const short8*)(a0h + ko);
        const short8 A1 = *(const short8*)(a1h + ko);
        const short8 L0 = *(const short8*)(a0l + ko);
        const short8 L1 = *(const short8*)(a1l + ko);
#pragma unroll
        for (int c = 0; c < 4; ++c) {
            const short8 Bh = *(const short8*)(bh0 + c * (16 * 512) + ko);
            const short8 Bl = *(const short8*)(bl0 + c * (16 * 512) + ko);
            acc[0][c] = __builtin_amdgcn_mfma_f32_16x16x32_bf16(A0, Bh, acc[0][c], 0, 0, 0);
            acc[1][c] = __builtin_amdgcn_mfma_f32_16x16x32_bf16(A1, Bh, acc[1][c], 0, 0, 0);
            acc[0][c] = __builtin_amdgcn_mfma_f32_16x16x32_bf16(A0, Bl, acc[0][c], 0, 0, 0);
            acc[1][c] = __builtin_amdgcn_mfma_f32_16x16x32_bf16(A1, Bl, acc[1][c], 0, 0, 0);
            acc[0][c] = __builtin_amdgcn_mfma_f32_16x16x32_bf16(L0, Bh, acc[0][c], 0, 0, 0);
            acc[1][c] = __builtin_amdgcn_mfma_f32_16x16x32_bf16(L1, Bh, acc[1][c], 0, 0, 0);
        }
    }

    float ws2c[4];
#pragma unroll
    for (int c = 0; c < 4; ++c) ws2c[c] = Ws2[j0 + c * 16 + l15];
#pragma unroll
    for (int g = 0; g < 2; ++g)
#pragma unroll
        for (int r = 0; r < 4; ++r) {
            float p = 0.0f;
#pragma unroll
            for (int c = 0; c < 4; ++c) {
                const float hv = acc[g][c][r];
                p = fmaf(0.5f * hv * (1.0f + erff(hv * 0.70710678118f)), ws2c[c], p);
            }
            p += __shfl_xor(p, 1); p += __shfl_xor(p, 2);
            p += __shfl_xor(p, 4); p += __shfl_xor(p, 8);
            if (l15 == 0) red[w][g * 16 + l4 * 4 + r] = p;
        }
    __syncthreads();
    if (tid < 32)
        imp[tok0 + tid] = (red[0][tid] + red[1][tid]) + (red[2][tid] + red[3][tid]);
}

// ---------------------------------------------------------------------------
// Per-batch exact top-k via radix-select, then index-ordered tie resolution
// (matches jax.lax.top_k selected SET). One block (1024 thr) per batch.
// ---------------------------------------------------------------------------
__global__ __launch_bounds__(1024) void topk_select_k(
    const float* __restrict__ imp, unsigned char* __restrict__ sel)
{
    __shared__ unsigned int keys[4096];
    __shared__ unsigned int hist[256];
    __shared__ int chunkscan[64];
    __shared__ unsigned int sh_prefix;
    __shared__ int sh_rem;
    const int b = blockIdx.x, tid = threadIdx.x;
    const int lane = tid & 63, w = tid >> 6;
    for (int i = tid; i < 4096; i += 1024) {
        const unsigned int u = __float_as_uint(imp[b * 4096 + i]);
        keys[i] = (u & 0x80000000u) ? ~u : (u | 0x80000000u);  // order-preserving
    }
    if (tid == 0) { sh_prefix = 0u; sh_rem = TOPK_; }
    __syncthreads();
    unsigned int pmask = 0;
    for (int level = 3; level >= 0; --level) {
        const int shb = level * 8;
        const unsigned int prefix = sh_prefix;
        const int remaining = sh_rem;
        if (tid < 256) hist[tid] = 0;
        __syncthreads();
        for (int i = tid; i < 4096; i += 1024) {
            const unsigned int u = keys[i];
            if ((u & pmask) == prefix) atomicAdd(&hist[(u >> shb) & 255u], 1u);
        }
        __syncthreads();
        if (tid < 64) {
            unsigned int v[4];
            int tot = 0;
#pragma unroll
            for (int q = 0; q < 4; ++q) { v[q] = hist[255 - (tid * 4 + q)]; tot += (int)v[q]; }
            int pre = tot;
            for (int off = 1; off < 64; off <<= 1) {
                const int t = __shfl_up(pre, off);
                if (tid >= off) pre += t;
            }
            const unsigned long long bal = __ballot(pre >= remaining);
            const int L = __ffsll((unsigned long long)bal) - 1;
            if (tid == L) {
                int c = pre - tot;
#pragma unroll
                for (int q = 0; q < 4; ++q) {
                    c += (int)v[q];
                    if (c >= remaining) {
                        sh_rem = remaining - (c - (int)v[q]);
                        sh_prefix = prefix | ((unsigned int)(255 - (tid * 4 + q)) << shb);
                        break;
                    }
                }
            }
        }
        __syncthreads();
        pmask |= (255u << shb);
    }
    const unsigned int T = sh_prefix;
    const int need = sh_rem;  // how many == T elements to take (index asc)
#pragma unroll
    for (int q = 0; q < 4; ++q) {
        const int chunk = w * 4 + q;
        const unsigned long long bal = __ballot(keys[chunk * 64 + lane] == T);
        if (lane == 0) chunkscan[chunk] = __popcll(bal);
    }
    __syncthreads();
    if (tid < 64) {
        const int v = chunkscan[tid];
        int pre = v;
        for (int off = 1; off < 64; off <<= 1) {
            const int t = __shfl_up(pre, off);
            if (tid >= off) pre += t;
        }
        chunkscan[tid] = pre - v;  // exclusive prefix
    }
    __syncthreads();
#pragma unroll
    for (int q = 0; q < 4; ++q) {
        const int chunk = w * 4 + q;
        const int i = chunk * 64 + lane;
        const unsigned int u = keys[i];
        const bool eq = (u == T);
        const unsigned long long bal = __ballot(eq);
        const int rank = chunkscan[chunk] + __popcll(bal & ((1ull << lane) - 1ull));
        sel[b * 4096 + i] = (u > T || (eq && rank < need)) ? 1 : 0;
    }
}

// ---------------------------------------------------------------------------
// Union of selections -> compacted ascending column list + gather rowmap.
// Lane-parallel: lane i owns tokens i*64..i*64+63 (bitmask + shfl scan).
// ---------------------------------------------------------------------------
__global__ void compact_k(const unsigned char* __restrict__ sel,
                          int* __restrict__ rowmap, int* __restrict__ keffp)
{
    const int lane = threadIdx.x;  // 64 threads = 1 wave
    const unsigned long long* p0 = (const unsigned long long*)(sel);
    const unsigned long long* p1 = (const unsigned long long*)(sel + 4096);
    unsigned long long bits = 0;
#pragma unroll
    for (int q = 0; q < 8; ++q) {
        const unsigned long long u = p0[lane * 8 + q] | p1[lane * 8 + q];
        unsigned long long b8 = 0;
#pragma unroll
        for (int j = 0; j < 8; ++j) b8 |= ((u >> (8 * j)) & 1ull) << j;
        bits |= b8 << (8 * q);
    }
    const int cnt = __popcll(bits);
    int pre = cnt;
    for (int off = 1; off < 64; off <<= 1) {
        const int t = __shfl_up(pre, off);
        if (lane >= off) pre += t;
    }
    const int total = __shfl(pre, 63);
    int ofs = pre - cnt;  // exclusive prefix
    unsigned long long m = bits;
    while (m) {
        const int j = __ffsll(m) - 1;
        const int pos = lane * 64 + j;
        rowmap[ofs] = pos;                  // batch 0 token row
        rowmap[KSLOTS_ + ofs] = 4096 + pos; // batch 1 token row
        ++ofs;
        m &= m - 1;
    }
    for (int s = total + lane; s < KSLOTS_; s += 64) {
        rowmap[s] = 0; rowmap[KSLOTS_ + s] = 4096;  // pad -> token 0 (masked)
    }
    if (lane == 0) keffp[0] = total;
}

// ---------------------------------------------------------------------------
// Merged projection kernel (one launch, flat grid of 640 blocks):
//  id < 512:        Q-GEMM, LDS-staged (verified gemm128 single-buffer):
//                   q_all[m][n] = xb[m] @ WqT^T + bq*0.125, tiles (id>>3, id&7)
//  512 <= id < 576: K-proj (row gather): k_sel[s] = xb[rowmap[s]] @ Wk + bk
//  576 <= id:       V^T-proj (permuted cols): vT[d][col] = Wv^T[d].xb[...]+bv
// Q-tile path and K/V paths are independent outputs; pure launch fusion.
// ---------------------------------------------------------------------------
__global__ __launch_bounds__(256) void gemm_proj_k(
    const ushort_t* __restrict__ xb,
    const ushort_t* __restrict__ WqT, const float* __restrict__ bq,
    ushort_t* __restrict__ q_all,
    const ushort_t* __restrict__ WkT, const float* __restrict__ bk,
    ushort_t* __restrict__ k_sel,
    const ushort_t* __restrict__ WvT, const float* __restrict__ bv,
    ushort_t* __restrict__ vT, const int* __restrict__ rowmap)
{
    const int K = 512;
    const int tid = threadIdx.x, lane = tid & 63, w = tid >> 6;
    const int l15 = lane & 15, l4 = lane >> 4;
    const int id = blockIdx.x;

    if (id < 512) {
        // ---- Q projection: LDS-staged 128x64 tile, T2 XOR swizzle ----
        __shared__ __align__(16) ushort_t Al[128 * 64];
        __shared__ __align__(16) ushort_t Bl[64 * 64];
        const int m0 = (id >> 3) * 128, n0 = (id & 7) * 64;
        const int row_off = lane >> 3, kq = lane & 7;
        const int src_k8 = (kq ^ row_off) * 8;   // inverse-swizzled source

        f32x4 acc[2][4] = {};
#pragma unroll 1
        for (int kt = 0; kt < 8; ++kt) {
            __syncthreads();  // all waves done reading previous tile
#pragma unroll
            for (int i = 0; i < 4; ++i) {
                const int ia = w * 4 + i;
                const long ga = (long)(m0 + ia * 8 + row_off) * 512 + kt * 64 + src_k8;
                __builtin_amdgcn_global_load_lds((const g_u32*)(xb + ga),
                                                 (l_u32*)(Al + ia * 512), 16, 0, 0);
            }
#pragma unroll
            for (int i = 0; i < 2; ++i) {
                const int ib = w * 2 + i;
                const long gb = (long)(n0 + ib * 8 + row_off) * 512 + kt * 64 + src_k8;
                __builtin_amdgcn_global_load_lds((const g_u32*)(WqT + gb),
                                                 (l_u32*)(Bl + ib * 512), 16, 0, 0);
            }
            __syncthreads();  // tile ready
#pragma unroll
            for (int kh = 0; kh < 2; ++kh) {
                short8 af[2], bfr[4];
#pragma unroll
                for (int t = 0; t < 2; ++t) {
                    const int row = w * 32 + t * 16 + l15;
                    const int c8 = (kh * 4 + l4) ^ (row & 7);
                    af[t] = *(const short8*)(Al + row * 64 + c8 * 8);
                }
#pragma unroll
                for (int u = 0; u < 4; ++u) {
                    const int col = u * 16 + l15;
                    const int c8 = (kh * 4 + l4) ^ (col & 7);
                    bfr[u] = *(const short8*)(Bl + col * 64 + c8 * 8);
                }
#pragma unroll
                for (int t = 0; t < 2; ++t)
#pragma unroll
                    for (int u = 0; u < 4; ++u)
                        acc[t][u] = __builtin_amdgcn_mfma_f32_16x16x32_bf16(
                            af[t], bfr[u], acc[t][u], 0, 0, 0);
            }
        }
#pragma unroll
        for (int t = 0; t < 2; ++t)
#pragma unroll
            for (int u = 0; u < 4; ++u) {
                const int col = n0 + u * 16 + l15;
                const float bvv = bq[col] * 0.125f;
#pragma unroll
                for (int r = 0; r < 4; ++r) {
                    const int row = m0 + w * 32 + t * 16 + l4 * 4 + r;
                    q_all[(long)row * 512 + col] = f2bf(acc[t][u][r] + bvv);
                }
            }
    } else if (id < 576) {
        // ---- K projection (row gather) ----
        const int kid = id - 512;
        const int m_base = (kid & 7) * 128 + w * 32;
        const int n_base = (kid >> 3) * 64;
        const long ar0 = (long)rowmap[m_base + l15];
        const long ar1 = (long)rowmap[m_base + 16 + l15];
        const ushort_t* a0p = xb + ar0 * K + l4 * 8;
        const ushort_t* a1p = xb + ar1 * K + l4 * 8;
        const ushort_t* bp0 = WkT + (long)(n_base +  0 + l15) * K + l4 * 8;
        const ushort_t* bp1 = WkT + (long)(n_base + 16 + l15) * K + l4 * 8;
        const ushort_t* bp2 = WkT + (long)(n_base + 32 + l15) * K + l4 * 8;
        const ushort_t* bp3 = WkT + (long)(n_base + 48 + l15) * K + l4 * 8;
        f32x4 acc[2][4] = {};
#pragma unroll 4
        for (int kk = 0; kk < 16; ++kk) {
            const int ko = kk * 32;
            const short8 a0 = *(const short8*)(a0p + ko);
            const short8 a1 = *(const short8*)(a1p + ko);
            const short8 b0 = *(const short8*)(bp0 + ko);
            const short8 b1 = *(const short8*)(bp1 + ko);
            const short8 b2 = *(const short8*)(bp2 + ko);
            const short8 b3 = *(const short8*)(bp3 + ko);
            acc[0][0] = __builtin_amdgcn_mfma_f32_16x16x32_bf16(a0, b0, acc[0][0], 0, 0, 0);
            acc[1][0] = __builtin_amdgcn_mfma_f32_16x16x32_bf16(a1, b0, acc[1][0], 0, 0, 0);
            acc[0][1] = __builtin_amdgcn_mfma_f32_16x16x32_bf16(a0, b1, acc[0][1], 0, 0, 0);
            acc[1][1] = __builtin_amdgcn_mfma_f32_16x16x32_bf16(a1, b1, acc[1][1], 0, 0, 0);
            acc[0][2] = __builtin_amdgcn_mfma_f32_16x16x32_bf16(a0, b2, acc[0][2], 0, 0, 0);
            acc[1][2] = __builtin_amdgcn_mfma_f32_16x16x32_bf16(a1, b2, acc[1][2], 0, 0, 0);
            acc[0][3] = __builtin_amdgcn_mfma_f32_16x16x32_bf16(a0, b3, acc[0][3], 0, 0, 0);
            acc[1][3] = __builtin_amdgcn_mfma_f32_16x16x32_bf16(a1, b3, acc[1][3], 0, 0, 0);
        }
#pragma unroll
        for (int g = 0; g < 2; ++g)
#pragma unroll
            for (int c = 0; c < 4; ++c) {
                const int col = n_base + c * 16 + l15;
                const float bvv = bk[col];
#pragma unroll
                for (int r = 0; r < 4; ++r) {
                    const int row = m_base + g * 16 + l4 * 4 + r;
                    k_sel[(long)row * 512 + col] = f2bf(acc[g][c][r] + bvv);
                }
            }
    } else {
        // ---- V^T projection with permuted columns ----
        const int vid = id - 576;
        const int m_base = (vid & 3) * 128 + w * 32;   // d
        const int n_base = (vid >> 2) * 64;            // b*512+slot (physical)
        const ushort_t* a0p = WvT + (long)(m_base + l15) * K + l4 * 8;
        const ushort_t* a1p = WvT + (long)(m_base + 16 + l15) * K + l4 * 8;
        const long c0 = rowmap[vperm(n_base +  0 + l15)];
        const long c1 = rowmap[vperm(n_base + 16 + l15)];
        const long c2 = rowmap[vperm(n_base + 32 + l15)];
        const long c3 = rowmap[vperm(n_base + 48 + l15)];
        const ushort_t* bp0 = xb + c0 * K + l4 * 8;
        const ushort_t* bp1 = xb + c1 * K + l4 * 8;
        const ushort_t* bp2 = xb + c2 * K + l4 * 8;
        const ushort_t* bp3 = xb + c3 * K + l4 * 8;
        f32x4 acc[2][4] = {};
#pragma unroll 4
        for (int kk = 0; kk < 16; ++kk) {
            const int ko = kk * 32;
            const short8 a0 = *(const short8*)(a0p + ko);
            const short8 a1 = *(const short8*)(a1p + ko);
            const short8 b0 = *(const short8*)(bp0 + ko);
            const short8 b1 = *(const short8*)(bp1 + ko);
            const short8 b2 = *(const short8*)(bp2 + ko);
            const short8 b3 = *(const short8*)(bp3 + ko);
            acc[0][0] = __builtin_amdgcn_mfma_f32_16x16x32_bf16(a0, b0, acc[0][0], 0, 0, 0);
            acc[1][0] = __builtin_amdgcn_mfma_f32_16x16x32_bf16(a1, b0, acc[1][0], 0, 0, 0);
            acc[0][1] = __builtin_amdgcn_mfma_f32_16x16x32_bf16(a0, b1, acc[0][1], 0, 0, 0);
            acc[1][1] = __builtin_amdgcn_mfma_f32_16x16x32_bf16(a1, b1, acc[1][1], 0, 0, 0);
            acc[0][2] = __builtin_amdgcn_mfma_f32_16x16x32_bf16(a0, b2, acc[0][2], 0, 0, 0);
            acc[1][2] = __builtin_amdgcn_mfma_f32_16x16x32_bf16(a1, b2, acc[1][2], 0, 0, 0);
            acc[0][3] = __builtin_amdgcn_mfma_f32_16x16x32_bf16(a0, b3, acc[0][3], 0, 0, 0);
            acc[1][3] = __builtin_amdgcn_mfma_f32_16x16x32_bf16(a1, b3, acc[1][3], 0, 0, 0);
        }
#pragma unroll
        for (int g = 0; g < 2; ++g)
#pragma unroll
            for (int r = 0; r < 4; ++r) {
                const int row = m_base + g * 16 + l4 * 4 + r;  // d
                const float bvv = bv[row];
#pragma unroll
                for (int c = 0; c < 4; ++c) {
                    const int col = n_base + c * 16 + l15;
                    vT[(long)row * 1024 + col] = f2bf(acc[g][c][r] + bvv);
                }
            }
    }
}

// ---------------------------------------------------------------------------
// LDS-staged GEMM (verified single-buffer), O-projection: d_out = att@Wo + bo.
// Tile 128x64, BK=64. global_load_lds width=16 with T2 XOR swizzle.
// ---------------------------------------------------------------------------
__global__ __launch_bounds__(256) void gemm128_k(
    const ushort_t* __restrict__ A, const ushort_t* __restrict__ WT,
    const float* __restrict__ bias, float* __restrict__ Cf)
{
    __shared__ __align__(16) ushort_t Al[128 * 64];
    __shared__ __align__(16) ushort_t Bl[64 * 64];
    const int tid = threadIdx.x, lane = tid & 63, w = tid >> 6;
    const int l15 = lane & 15, l4 = lane >> 4;
    const int m0 = blockIdx.x * 128, n0 = blockIdx.y * 64;
    const int row_off = lane >> 3, kq = lane & 7;
    const int src_k8 = (kq ^ row_off) * 8;

    f32x4 acc[2][4] = {};
#pragma unroll 1
    for (int kt = 0; kt < 8; ++kt) {
        __syncthreads();
#pragma unroll
        for (int i = 0; i < 4; ++i) {
            const int ia = w * 4 + i;
            const long ga = (long)(m0 + ia * 8 + row_off) * 512 + kt * 64 + src_k8;
            __builtin_amdgcn_global_load_lds((const g_u32*)(A + ga),
                                             (l_u32*)(Al + ia * 512), 16, 0, 0);
        }
#pragma unroll
        for (int i = 0; i < 2; ++i) {
            const int ib = w * 2 + i;
            const long gb = (long)(n0 + ib * 8 + row_off) * 512 + kt * 64 + src_k8;
            __builtin_amdgcn_global_load_lds((const g_u32*)(WT + gb),
                                             (l_u32*)(Bl + ib * 512), 16, 0, 0);
        }
        __syncthreads();
#pragma unroll
        for (int kh = 0; kh < 2; ++kh) {
            short8 af[2], bfr[4];
#pragma unroll
            for (int t = 0; t < 2; ++t) {
                const int row = w * 32 + t * 16 + l15;
                const int c8 = (kh * 4 + l4) ^ (row & 7);
                af[t] = *(const short8*)(Al + row * 64 + c8 * 8);
            }
#pragma unroll
            for (int u = 0; u < 4; ++u) {
                const int col = u * 16 + l15;
                const int c8 = (kh * 4 + l4) ^ (col & 7);
                bfr[u] = *(const short8*)(Bl + col * 64 + c8 * 8);
            }
#pragma unroll
            for (int t = 0; t < 2; ++t)
#pragma unroll
                for (int u = 0; u < 4; ++u)
                    acc[t][u] = __builtin_amdgcn_mfma_f32_16x16x32_bf16(
                        af[t], bfr[u], acc[t][u], 0, 0, 0);
        }
    }
#pragma unroll
    for (int t = 0; t < 2; ++t)
#pragma unroll
        for (int u = 0; u < 4; ++u) {
            const int col = n0 + u * 16 + l15;
            const float bvv = bias[col];
#pragma unroll
            for (int r = 0; r < 4; ++r) {
                const int row = m0 + w * 32 + t * 16 + l4 * 4 + r;
                Cf[(long)row * 512 + col] = acc[t][u][r] + bvv;
            }
        }
}

// ---------------------------------------------------------------------------
// Flash attention v5 (verified r9/r14): swapped QK^T (q lane-local) +
// pre-permuted V => P never leaves registers (zero LDS). cvt_pk packs P to
// bf16 A-fragments. Grid = B*H*(S/128) = 512 blocks; 4 waves x 32 q-rows.
// Q pre-scaled by HD^-0.5.
// ---------------------------------------------------------------------------
__global__ __launch_bounds__(256) void attn_k(
    const ushort_t* __restrict__ q_all, const ushort_t* __restrict__ k_sel,
    const ushort_t* __restrict__ vT, const int* __restrict__ keff_p,
    ushort_t* __restrict__ att)
{
    const int tid = threadIdx.x;
    const int lane = tid & 63, w = tid >> 6;
    const int l15 = lane & 15, l4 = lane >> 4;
    const int bidx = blockIdx.x;
    const int qt = bidx & 31, h = (bidx >> 5) & 7, b = bidx >> 8;
    const int q0 = qt * 128;
    const int keff = keff_p[0];
    const int nfull = keff >> 6;
    const int ntiles = (keff + 63) >> 6;

    // Q fragments (B operand; input col = q = l15)
    short8 qf[2][2];
#pragma unroll
    for (int g = 0; g < 2; ++g) {
        const ushort_t* qrow =
            q_all + (long)(b * 4096 + q0 + w * 32 + g * 16 + l15) * 512 + h * 64;
#pragma unroll
        for (int ks = 0; ks < 2; ++ks)
            qf[g][ks] = *(const short8*)(qrow + ks * 32 + l4 * 8);
    }

    f32x4 acc[2][4] = {};
    float mrun[2] = {-3.0e38f, -3.0e38f};
    float lrun[2] = {0.0f, 0.0f};

#pragma unroll 1
    for (int t = 0; t < ntiles; ++t) {
        // ---- swapped scores: D[key][q], q = l15, key = c*16 + l4*4 + r ----
        f32x4 s[2][4] = {};
#pragma unroll
        for (int c = 0; c < 4; ++c) {
            const ushort_t* krow =
                k_sel + (long)(b * KSLOTS_ + t * 64 + c * 16 + l15) * 512 + h * 64;
#pragma unroll
            for (int ks = 0; ks < 2; ++ks) {
                const short8 kf = *(const short8*)(krow + ks * 32 + l4 * 8);
                s[0][c] = __builtin_amdgcn_mfma_f32_16x16x32_bf16(kf, qf[0][ks], s[0][c], 0, 0, 0);
                s[1][c] = __builtin_amdgcn_mfma_f32_16x16x32_bf16(kf, qf[1][ks], s[1][c], 0, 0, 0);
            }
        }
        // ---- pad mask (stored-row coords), partial tile only ----
        if (t >= nfull) {
            const int rbase = t * 64 + l4 * 4;
#pragma unroll
            for (int c = 0; c < 4; ++c)
#pragma unroll
                for (int r = 0; r < 4; ++r) {
                    const bool valid = (rbase + c * 16 + r) < keff;
                    s[0][c][r] = valid ? s[0][c][r] : -1.0e30f;
                    s[1][c][r] = valid ? s[1][c][r] : -1.0e30f;
                }
        }
        // ---- per-thread row stats (all 16 values share q = l15) ----
        float mn[2];
        bool chg = false;
#pragma unroll
        for (int g = 0; g < 2; ++g) {
            float rm = -3.0e38f;
#pragma unroll
            for (int c = 0; c < 4; ++c)
                rm = fmaxf(rm, fmaxf(fmaxf(s[g][c][0], s[g][c][1]),
                                     fmaxf(s[g][c][2], s[g][c][3])));
            rm = fmaxf(rm, __shfl_xor(rm, 16));
            rm = fmaxf(rm, __shfl_xor(rm, 32));
            mn[g] = (rm > mrun[g] + 8.0f) ? rm : mrun[g];  // defer-max THR=8
            chg |= (mn[g] != mrun[g]);
        }
        if (__any(chg)) {
#pragma unroll
            for (int g = 0; g < 2; ++g) {
                const float sc = __expf(mrun[g] - mn[g]);
                lrun[g] *= sc;
#pragma unroll
                for (int r = 0; r < 4; ++r) {
                    const float scr = __shfl(sc, l4 * 4 + r);  // q of acc row r
#pragma unroll
                    for (int cd = 0; cd < 4; ++cd) acc[g][cd][r] *= scr;
                }
            }
        }
        mrun[0] = mn[0]; mrun[1] = mn[1];
#pragma unroll
        for (int g = 0; g < 2; ++g) {
            float rs = 0.0f;
#pragma unroll
            for (int c = 0; c < 4; ++c)
#pragma unroll
                for (int r = 0; r < 4; ++r) {
                    const float e = __expf(s[g][c][r] - mrun[g]);
                    s[g][c][r] = e;
                    rs += e;
                }
            rs += __shfl_xor(rs, 16);
            rs += __shfl_xor(rs, 32);
            lrun[g] += rs;
        }
        // ---- pack P into bf16 A-fragments (register-only; V pre-permuted) ----
        short8 pf[2][2];
#pragma unroll
        for (int g = 0; g < 2; ++g)
#pragma unroll
            for (int ks = 0; ks < 2; ++ks) {
                union { unsigned int u[4]; short8 v; } uu;
                asm("v_cvt_pk_bf16_f32 %0, %1, %2"
                    : "=v"(uu.u[0]) : "v"(s[g][2 * ks][0]), "v"(s[g][2 * ks][1]));
                asm("v_cvt_pk_bf16_f32 %0, %1, %2"
                    : "=v"(uu.u[1]) : "v"(s[g][2 * ks][2]), "v"(s[g][2 * ks][3]));
                asm("v_cvt_pk_bf16_f32 %0, %1, %2"
                    : "=v"(uu.u[2]) : "v"(s[g][2 * ks + 1][0]), "v"(s[g][2 * ks + 1][1]));
                asm("v_cvt_pk_bf16_f32 %0, %1, %2"
                    : "=v"(uu.u[3]) : "v"(s[g][2 * ks + 1][2]), "v"(s[g][2 * ks + 1][3]));
                pf[g][ks] = uu.v;
            }
        // ---- PV: O += P @ V ----
#pragma unroll
        for (int cd = 0; cd < 4; ++cd) {
            const ushort_t* vrow =
                vT + (long)(h * 64 + cd * 16 + l15) * 1024 + b * 512 + t * 64;
#pragma unroll
            for (int ks = 0; ks < 2; ++ks) {
                const short8 vf = *(const short8*)(vrow + ks * 32 + l4 * 8);
                acc[0][cd] = __builtin_amdgcn_mfma_f32_16x16x32_bf16(pf[0][ks], vf, acc[0][cd], 0, 0, 0);
                acc[1][cd] = __builtin_amdgcn_mfma_f32_16x16x32_bf16(pf[1][ks], vf, acc[1][cd], 0, 0, 0);
            }
        }
    }
    // ---- normalize + store: acc row r has q = l4*4 + r ----
#pragma unroll
    for (int g = 0; g < 2; ++g)
#pragma unroll
        for (int r = 0; r < 4; ++r) {
            const float lr = __shfl(lrun[g], l4 * 4 + r);
            const float inv = 1.0f / lr;
            const int row = q0 + w * 32 + g * 16 + l4 * 4 + r;
#pragma unroll
            for (int cd = 0; cd < 4; ++cd)
                att[(long)(b * 4096 + row) * 512 + h * 64 + cd * 16 + l15] =
                    f2bf(acc[g][cd][r] * inv);
        }
}

// ---------------------------------------------------------------------------
extern "C" void kernel_launch(void* const* d_in, const int* in_sizes, int n_in,
                              void* d_out, int out_size, void* d_ws, size_t ws_size,
                              hipStream_t stream)
{
    const float* x   = (const float*)d_in[0];
    const float* Wq  = (const float*)d_in[1];
    const float* bq  = (const float*)d_in[2];
    const float* Wk  = (const float*)d_in[3];
    const float* bk  = (const float*)d_in[4];
    const float* Wv  = (const float*)d_in[5];
    const float* bv  = (const float*)d_in[6];
    const float* Wo  = (const float*)d_in[7];
    const float* bo  = (const float*)d_in[8];
    const float* Ws1 = (const float*)d_in[9];
    const float* bs1 = (const float*)d_in[10];
    const float* Ws2 = (const float*)d_in[11];
    // d_in[12] = bs2 (selection-invariant, unused), d_in[13] = top_k (=256)

    char* ws = (char*)d_ws;
    float*          imp    = (float*)(ws + 0);              // 32 KB
    unsigned char*  sel    = (unsigned char*)(ws + 0x8000); // 8 KB
    int*            keffp  = (int*)(ws + 0xA800);
    int*            rowmap = (int*)(ws + 0xB000);           // 4 KB
    ushort_t*  WqT    = (ushort_t*)(ws + 0x40000);          // 4 x 512 KB
    ushort_t*  WkT    = WqT + 512 * 512;
    ushort_t*  WvT    = WkT + 512 * 512;
    ushort_t*  WoT    = WvT + 512 * 512;
    ushort_t*  k_sel  = (ushort_t*)(ws + 0x240000);         // 1 MB
    ushort_t*  vT     = (ushort_t*)(ws + 0x340000);         // 1 MB
    ushort_t*  w1hi   = (ushort_t*)(ws + 0x440000);         // 256 KB
    ushort_t*  w1lo   = (ushort_t*)(ws + 0x480000);         // 256 KB
    ushort_t*  xb     = (ushort_t*)(ws + 0x600000);         // 8 MB (= x_hi; reused as att)
    ushort_t*  att    = xb;                                 // dead after projections
    ushort_t*  xlo    = (ushort_t*)(ws + 0xE00000);         // 8 MB (reused as q_all)
    ushort_t*  q_all  = xlo;                                // xlo dead after imp_mfma

    const dim3 tblk(256);
    // 1. fused prep: x hi/lo pack + all weight transposes (Wq scaled 0.125)
    prep_k<<<3328, tblk, 0, stream>>>(x, xb, xlo, Wq, Wk, Wv, Wo, Ws1,
                                      WqT, WkT, WvT, WoT, w1hi, w1lo);
    // 2. importance via hi/lo MFMA (selection-exact vs fp32)
    imp_mfma_k<<<256, tblk, 0, stream>>>(xb, xlo, w1hi, w1lo, bs1, Ws2, imp);
    // 3. per-batch top-k via radix select
    topk_select_k<<<2, 1024, 0, stream>>>(imp, sel);
    // 4. union mask -> compacted column list + gather map (lane-parallel)
    compact_k<<<1, 64, 0, stream>>>(sel, rowmap, keffp);
    // 5. merged projections: Q (LDS-staged, 0.125-scaled; overwrites xlo —
    //    dead) + gathered K + permuted V^T, one 640-block launch
    gemm_proj_k<<<640, tblk, 0, stream>>>(xb, WqT, bq, q_all,
                                          WkT, bk, k_sel, WvT, bv, vT, rowmap);
    // 6. sparse flash attention v5 (att overwrites xb region — xb is dead now)
    attn_k<<<512, tblk, 0, stream>>>(q_all, k_sel, vT, keffp, att);
    // 7. output projection (LDS-staged) -> d_out (fp32)
    gemm128_k<<<dim3(64, 8), tblk, 0, stream>>>(att, WoT, bo, (float*)d_out);
}